// Round 8
// baseline (1009.494 us; speedup 1.0000x reference)
//
#include <hip/hip_runtime.h>

#define NN 50000
#define KSEQ 20
#define HN_OFF 6400000   // N*128
#define CN_OFF 12800000  // 2*N*128

using short8 = __attribute__((ext_vector_type(8))) short;
using f32x4  = __attribute__((ext_vector_type(4))) float;

__device__ __forceinline__ unsigned short f2bf(float f) {
    unsigned int u = __float_as_uint(f);
    return (unsigned short)((u + 0x7FFFu + ((u >> 16) & 1u)) >> 16);  // RNE
}
__device__ __forceinline__ float exp2x(float x) { float r; asm("v_exp_f32 %0, %1" : "=v"(r) : "v"(x)); return r; }
__device__ __forceinline__ float rcpx(float x)  { float r; asm("v_rcp_f32 %0, %1" : "=v"(r) : "v"(x)); return r; }

#define L2E 1.4426950408889634f
// inputs PRE-SCALED in prep: sigmoid weights by -l2e, tanh(g) weights by +2*l2e
__device__ __forceinline__ float sigp(float y)  { return rcpx(1.f + exp2x(y)); }
__device__ __forceinline__ float tanhp(float y) { return fmaf(-2.f, rcpx(1.f + exp2x(y)), 1.f); }

// ---- prep: bf16 weight packs (pre-scaled LSTM weights, transposes, bias sum) ----
__global__ void prep_kernel(const float* __restrict__ Wp, const float* __restrict__ W,
                            const float* __restrict__ Wih, const float* __restrict__ Whh,
                            const float* __restrict__ bih, const float* __restrict__ bhh,
                            unsigned short* __restrict__ Wih_b, unsigned short* __restrict__ Whh_b,
                            unsigned short* __restrict__ Wpt, unsigned short* __restrict__ Wtt,
                            float* __restrict__ bsum) {
    int tid = blockIdx.x * blockDim.x + threadIdx.x;
    if (tid < 65536) {  // gate scale: i,f,o -> -l2e ; g -> +2*l2e
        float sc = ((tid >> 14) == 2) ? (2.f * L2E) : (-L2E);
        Wih_b[tid] = f2bf(Wih[tid] * sc); return;
    }
    tid -= 65536;
    if (tid < 65536) {
        float sc = ((tid >> 14) == 2) ? (2.f * L2E) : (-L2E);
        Whh_b[tid] = f2bf(Whh[tid] * sc); return;
    }
    tid -= 65536;
    if (tid < 32768) { int j = tid >> 8, k = tid & 255; Wpt[tid] = f2bf(Wp[k * 128 + j]); return; }
    tid -= 32768;
    if (tid < 32768) { int j = tid >> 8, k = tid & 255; Wtt[tid] = f2bf(W[k * 128 + j]); return; }
    tid -= 32768;
    if (tid < 512) {
        float sc = ((tid >> 7) == 2) ? (2.f * L2E) : (-L2E);
        bsum[tid] = (bih[tid] + bhh[tid]) * sc;
    }
}

// ---- K1: hp = bf16(h @ W_past), 32 rows/block, 8 waves (16 cols each) ----
__global__ __launch_bounds__(512, 2) void hp_kernel(const float* __restrict__ h,
                                                    const unsigned short* __restrict__ Wpt,
                                                    unsigned short* __restrict__ hp_bf) {
    __shared__ __align__(16) unsigned char smem[32 * 512];
    const int tid = threadIdx.x;
    const int w = tid >> 6, l = tid & 63;
    const int l15 = l & 15, lq = l >> 4;
    const int base = blockIdx.x * 32;

#pragma unroll
    for (int i = 0; i < 4; ++i) {
        int chunk = tid + 512 * i;
        int row = chunk >> 6, kc = chunk & 63;
        int grow = base + row;
        float4 v = make_float4(0.f, 0.f, 0.f, 0.f);
        if (grow < NN) v = *(const float4*)(h + (size_t)grow * 256 + kc * 4);
        ushort4 bv = make_ushort4(f2bf(v.x), f2bf(v.y), f2bf(v.z), f2bf(v.w));
        int off = (row * 512 + kc * 8) ^ ((row & 7) << 4);
        *(ushort4*)(smem + off) = bv;
    }
    __syncthreads();

    const int jb = w * 16 + l15;
    short8 bf[8];
#pragma unroll
    for (int kt = 0; kt < 8; ++kt)
        bf[kt] = *(const short8*)((const unsigned char*)Wpt + jb * 512 + kt * 64 + lq * 16);

    f32x4 acc[2];
    acc[0] = (f32x4){0.f, 0.f, 0.f, 0.f};
    acc[1] = (f32x4){0.f, 0.f, 0.f, 0.f};
#pragma unroll
    for (int kt = 0; kt < 8; ++kt) {
#pragma unroll
        for (int rt = 0; rt < 2; ++rt) {
            int arow = rt * 16 + l15;
            int off = (arow * 512 + kt * 64 + lq * 16) ^ ((arow & 7) << 4);
            short8 a = *(const short8*)(smem + off);
            acc[rt] = __builtin_amdgcn_mfma_f32_16x16x32_bf16(a, bf[kt], acc[rt], 0, 0, 0);
        }
    }
#pragma unroll
    for (int rt = 0; rt < 2; ++rt)
#pragma unroll
        for (int r = 0; r < 4; ++r) {
            int row = rt * 16 + lq * 4 + r;
            int grow = base + row;
            if (grow < NN) hp_bf[(size_t)grow * 128 + w * 16 + l15] = f2bf(acc[rt][r]);
        }
}

// ---- K2: 8-wave wave-self-contained LSTM, 64 rows/block = 2 groups of 32.
// Wave w owns ALL 4 gates for cols w*16..w*16+15 (bw = 128 regs, AGPR).
// Phase X(t): A-waves gather x_A(t+1) | MFMA_A(t) (64 MFMA) | update_B(t-1) | A-store
// Phase Y(t): B-waves gather x_B(t+1) | MFMA_B(t)           | update_A(t)   | B-store
// LDS (48KB): xA[2] @0/@8192, xB[2] @16384/@24576, hA @32768, hB @40960
#define XB0 16384
#define HA  32768
#define HB  40960

__device__ __forceinline__ void gemm_group(const unsigned char* lds, int abase, int off0,
                                           const short8 (&bw)[4][8], int k0, f32x4 (&acc)[4][2]) {
#pragma unroll
    for (int kt = 0; kt < 4; ++kt) {
#pragma unroll
        for (int rt = 0; rt < 2; ++rt) {
            short8 a = *(const short8*)(lds + abase + rt * 4096 + (off0 ^ (kt << 6)));
#pragma unroll
            for (int g = 0; g < 4; ++g)
                acc[g][rt] = __builtin_amdgcn_mfma_f32_16x16x32_bf16(a, bw[g][k0 + kt], acc[g][rt], 0, 0, 0);
        }
    }
}

__device__ __forceinline__ void cell_update(f32x4 (&acc)[4][2], f32x4 (&cst)[2],
                                            unsigned char* hb, const int hb0, const int hswz,
                                            bool last, int growbase, int colj, int lq,
                                            float* __restrict__ out) {
#pragma unroll
    for (int rt = 0; rt < 2; ++rt)
#pragma unroll
        for (int e = 0; e < 4; ++e) {
            float c = fmaf(sigp(acc[1][rt][e]), cst[rt][e], sigp(acc[0][rt][e]) * tanhp(acc[2][rt][e]));
            cst[rt][e] = c;
            float hv = sigp(acc[3][rt][e]) * tanhp((2.f * L2E) * c);
            unsigned pk;
            asm("v_cvt_pk_bf16_f32 %0, %1, %2" : "=v"(pk) : "v"(hv), "v"(hv));
            *(unsigned short*)(hb + ((hb0 + rt * 4096 + e * 256) ^ (hswz ^ (e << 4)))) = (unsigned short)pk;
            if (last) {
                int grow = growbase + rt * 16 + lq * 4 + e;
                if (grow < NN) {
                    out[HN_OFF + (size_t)grow * 128 + colj] = hv;
                    out[CN_OFF + (size_t)grow * 128 + colj] = c;
                }
            }
        }
}

__global__ __launch_bounds__(512, 2) void lstm_kernel(const unsigned short* __restrict__ hp_bf,
                                                      const int* __restrict__ agg,
                                                      const unsigned short* __restrict__ Wih_b,
                                                      const unsigned short* __restrict__ Whh_b,
                                                      const unsigned short* __restrict__ Wtt,
                                                      const float* __restrict__ bsum,
                                                      float* __restrict__ out) {
    __shared__ __align__(16) unsigned char lds[49152];
    const int tid = threadIdx.x;
    const int w = tid >> 6, l = tid & 63;
    const int l15 = l & 15, lq = l >> 4;
    const int base = blockIdx.x * 64;
    const int colj = w * 16 + l15;
    const int wb = w >> 2;                  // 0: wave stages group A, 1: group B
    const int wg = w & 3;

    // weights: 4 gates x 8 k-tiles (0..3: W_ih/x, 4..7: W_hh/h) -> 128 regs (AGPR)
    short8 bw[4][8];
    float bi[4];
#pragma unroll
    for (int g = 0; g < 4; ++g) {
        const int j = g * 128 + colj;
#pragma unroll
        for (int kt = 0; kt < 4; ++kt) {
            bw[g][kt]     = *(const short8*)((const unsigned char*)Wih_b + j * 256 + kt * 64 + lq * 16);
            bw[g][kt + 4] = *(const short8*)((const unsigned char*)Whh_b + j * 256 + kt * 64 + lq * 16);
        }
        bi[g] = bsum[j];
    }

    // A-frag base offset within a 4KB 16x128 tile; rt adds 4096, kt XORs kt<<6
    const int off0 = (l15 * 256 + lq * 16) ^ ((l15 & 7) << 4);
    // h-write base: row = rt*16 + lq*4 + e
    const int hb0 = lq * 1024 + colj * 2;
    const int hswz = (lq & 1) << 6;

    // staging: lane covers rows r1, r2 (in-group), 16B chunk l15
    const int r1 = wg * 8 + lq, r2 = r1 + 4;
    const int g1 = base + wb * 32 + r1, g2 = base + wb * 32 + r2;
    const int sg1 = g1 < NN ? g1 : NN - 1, sg2 = g2 < NN ? g2 : NN - 1;
    const int a1 = sg1 * KSEQ, a2 = sg2 * KSEQ;
    const int xw1 = (r1 * 256 + l15 * 16) ^ ((r1 & 7) << 4);
    const int xw2 = (r2 * 256 + l15 * 16) ^ ((r2 & 7) << 4);
    const int stgbase = wb ? XB0 : 0;
    const unsigned char* hp8 = (const unsigned char*)hp_bf;

    // prologue: stage x(0) for own rows; prefetch idx(1)
    {
        int i1 = agg[a1], i2 = agg[a2];
        *(uint4*)(lds + stgbase + xw1) = *(const uint4*)(hp8 + (size_t)i1 * 256 + l15 * 16);
        *(uint4*)(lds + stgbase + xw2) = *(const uint4*)(hp8 + (size_t)i2 * 256 + l15 * 16);
    }
    int nidx1 = agg[a1 + 1], nidx2 = agg[a2 + 1];
    __syncthreads();

    f32x4 cstA[2], cstB[2];
    cstA[0] = (f32x4){0.f, 0.f, 0.f, 0.f}; cstA[1] = cstA[0];
    cstB[0] = cstA[0]; cstB[1] = cstA[0];
    f32x4 accA[4][2], accB[4][2];

#pragma unroll 1
    for (int t = 0; t < KSEQ; ++t) {
        const int par = (t & 1) << 13;

        // ================= phase X(t) =================
        uint4 v1, v2;
        if (!wb) {  // gather x_A(t+1); t=19 gathers own hp row (for epilogue)
            v1 = *(const uint4*)(hp8 + (size_t)nidx1 * 256 + l15 * 16);
            v2 = *(const uint4*)(hp8 + (size_t)nidx2 * 256 + l15 * 16);
            if (t <= 17) { nidx1 = agg[a1 + t + 2]; nidx2 = agg[a2 + t + 2]; }
            else         { nidx1 = sg1;             nidx2 = sg2; }
        }
#pragma unroll
        for (int g = 0; g < 4; ++g) { accA[g][0] = (f32x4){bi[g], bi[g], bi[g], bi[g]}; accA[g][1] = accA[g][0]; }
        __builtin_amdgcn_s_setprio(1);
        gemm_group(lds, par, off0, bw, 0, accA);            // x_A(t)
        if (t > 0) gemm_group(lds, HA, off0, bw, 4, accA);  // h_A(t)
        __builtin_amdgcn_s_setprio(0);
        if (t > 0) cell_update(accB, cstB, lds + HB, hb0, hswz, false, 0, colj, lq, out);
        if (!wb) {
            *(uint4*)(lds + (par ^ 8192) + xw1) = v1;
            *(uint4*)(lds + (par ^ 8192) + xw2) = v2;
        }
        __syncthreads();

        // ================= phase Y(t) =================
        if (wb) {   // gather x_B(t+1)
            v1 = *(const uint4*)(hp8 + (size_t)nidx1 * 256 + l15 * 16);
            v2 = *(const uint4*)(hp8 + (size_t)nidx2 * 256 + l15 * 16);
            if (t <= 17) { nidx1 = agg[a1 + t + 2]; nidx2 = agg[a2 + t + 2]; }
            else         { nidx1 = sg1;             nidx2 = sg2; }
        }
#pragma unroll
        for (int g = 0; g < 4; ++g) { accB[g][0] = (f32x4){bi[g], bi[g], bi[g], bi[g]}; accB[g][1] = accB[g][0]; }
        __builtin_amdgcn_s_setprio(1);
        gemm_group(lds, XB0 + par, off0, bw, 0, accB);      // x_B(t)
        if (t > 0) gemm_group(lds, HB, off0, bw, 4, accB);  // h_B(t)
        __builtin_amdgcn_s_setprio(0);
        cell_update(accA, cstA, lds + HA, hb0, hswz, t == KSEQ - 1, base, colj, lq, out);
        if (wb) {
            *(uint4*)(lds + XB0 + (par ^ 8192) + xw1) = v1;
            *(uint4*)(lds + XB0 + (par ^ 8192) + xw2) = v2;
        }
        __syncthreads();
    }

    // final update_B(19): hB + global h_n/c_n for B rows
    cell_update(accB, cstB, lds + HB, hb0, hswz, true, base + 32, colj, lq, out);
    __syncthreads();  // hA=h_A(20), hB=h_B(20), xA[0]/xB[0] = own hp rows

    // epilogue: out = elu([hp | h_n] @ W); 4 row-tiles of 16, per wave 16 out-cols
    short8 bo[8];
#pragma unroll
    for (int kt = 0; kt < 8; ++kt)
        bo[kt] = *(const short8*)((const unsigned char*)Wtt + colj * 512 + kt * 64 + lq * 16);

#pragma unroll
    for (int tb = 0; tb < 4; ++tb) {
        const int xb = (tb >> 1) ? XB0 : 0;
        const int hb = (tb >> 1) ? HB : HA;
        const int rt = (tb & 1) * 4096;
        f32x4 a2 = (f32x4){0.f, 0.f, 0.f, 0.f};
#pragma unroll
        for (int kt = 0; kt < 4; ++kt) {
            short8 a = *(const short8*)(lds + xb + rt + (off0 ^ (kt << 6)));   // hp
            a2 = __builtin_amdgcn_mfma_f32_16x16x32_bf16(a, bo[kt], a2, 0, 0, 0);
        }
#pragma unroll
        for (int kt = 0; kt < 4; ++kt) {
            short8 a = *(const short8*)(lds + hb + rt + (off0 ^ (kt << 6)));   // h_n
            a2 = __builtin_amdgcn_mfma_f32_16x16x32_bf16(a, bo[kt + 4], a2, 0, 0, 0);
        }
#pragma unroll
        for (int e = 0; e < 4; ++e) {
            int grow = base + tb * 16 + lq * 4 + e;
            if (grow < NN) {
                float v = a2[e];
                out[(size_t)grow * 128 + colj] = (v > 0.f) ? v : (exp2x(L2E * v) - 1.f);
            }
        }
    }
}

extern "C" void kernel_launch(void* const* d_in, const int* in_sizes, int n_in,
                              void* d_out, int out_size, void* d_ws, size_t ws_size,
                              hipStream_t stream) {
    (void)in_sizes; (void)n_in; (void)out_size; (void)ws_size;
    const float* h   = (const float*)d_in[0];
    const int*   agg = (const int*)d_in[1];
    const float* Wp  = (const float*)d_in[2];
    const float* W   = (const float*)d_in[3];
    const float* Wih = (const float*)d_in[4];
    const float* Whh = (const float*)d_in[5];
    const float* bih = (const float*)d_in[6];
    const float* bhh = (const float*)d_in[7];
    float* out = (float*)d_out;

    unsigned short* hp_bf = (unsigned short*)d_ws;       // 50000*128 bf16
    unsigned short* Wih_b = hp_bf + 6400000;             // 512*128 (pre-scaled)
    unsigned short* Whh_b = Wih_b + 65536;               // 512*128 (pre-scaled)
    unsigned short* Wpt   = Whh_b + 65536;               // 128*256 (W_past^T)
    unsigned short* Wtt   = Wpt + 32768;                 // 128*256 (W^T)
    float*          bsum  = (float*)(Wtt + 32768);       // 512 (pre-scaled)

    prep_kernel<<<771, 256, 0, stream>>>(Wp, W, Wih, Whh, bih, bhh, Wih_b, Whh_b, Wpt, Wtt, bsum);
    hp_kernel<<<1563, 512, 0, stream>>>(h, Wpt, hp_bf);
    lstm_kernel<<<782, 512, 0, stream>>>(hp_bf, agg, Wih_b, Whh_b, Wtt, bsum, out);
}

// Round 9
// 383.018 us; speedup vs baseline: 2.6356x; 2.6356x over previous
//
#include <hip/hip_runtime.h>

#define NN 50000
#define KSEQ 20
#define HN_OFF 6400000   // N*128
#define CN_OFF 12800000  // 2*N*128

using short8 = __attribute__((ext_vector_type(8))) short;
using f32x4  = __attribute__((ext_vector_type(4))) float;

__device__ __forceinline__ unsigned short f2bf(float f) {
    unsigned int u = __float_as_uint(f);
    return (unsigned short)((u + 0x7FFFu + ((u >> 16) & 1u)) >> 16);  // RNE
}
__device__ __forceinline__ float exp2x(float x) { float r; asm("v_exp_f32 %0, %1" : "=v"(r) : "v"(x)); return r; }
__device__ __forceinline__ float rcpx(float x)  { float r; asm("v_rcp_f32 %0, %1" : "=v"(r) : "v"(x)); return r; }

#define L2E 1.4426950408889634f
// gate pre-activations arrive PRE-SCALED (i,f,o by -l2e; g by +2*l2e)
__device__ __forceinline__ float sigp(float y)  { return rcpx(1.f + exp2x(y)); }
__device__ __forceinline__ float tanhp(float y) { return fmaf(-2.f, rcpx(1.f + exp2x(y)), 1.f); }

// ---- prep: bf16 weight packs (pre-scaled LSTM weights, transposes, bias sum) ----
__global__ void prep_kernel(const float* __restrict__ Wp, const float* __restrict__ W,
                            const float* __restrict__ Wih, const float* __restrict__ Whh,
                            const float* __restrict__ bih, const float* __restrict__ bhh,
                            unsigned short* __restrict__ Wih_b, unsigned short* __restrict__ Whh_b,
                            unsigned short* __restrict__ Wpt, unsigned short* __restrict__ Wtt,
                            float* __restrict__ bsum) {
    int tid = blockIdx.x * blockDim.x + threadIdx.x;
    if (tid < 65536) {  // gate scale: i,f,o -> -l2e ; g -> +2*l2e
        float sc = ((tid >> 14) == 2) ? (2.f * L2E) : (-L2E);
        Wih_b[tid] = f2bf(Wih[tid] * sc); return;
    }
    tid -= 65536;
    if (tid < 65536) {
        float sc = ((tid >> 14) == 2) ? (2.f * L2E) : (-L2E);
        Whh_b[tid] = f2bf(Whh[tid] * sc); return;
    }
    tid -= 65536;
    if (tid < 32768) { int j = tid >> 8, k = tid & 255; Wpt[tid] = f2bf(Wp[k * 128 + j]); return; }
    tid -= 32768;
    if (tid < 32768) { int j = tid >> 8, k = tid & 255; Wtt[tid] = f2bf(W[k * 128 + j]); return; }
    tid -= 32768;
    if (tid < 512) {
        float sc = ((tid >> 7) == 2) ? (2.f * L2E) : (-L2E);
        bsum[tid] = (bih[tid] + bhh[tid]) * sc;
    }
}

// ---- K1: hp = bf16(h @ W_past), 32 rows/block, 8 waves (16 cols each) ----
__global__ __launch_bounds__(512, 2) void hp_kernel(const float* __restrict__ h,
                                                    const unsigned short* __restrict__ Wpt,
                                                    unsigned short* __restrict__ hp_bf) {
    __shared__ __align__(16) unsigned char smem[32 * 512];
    const int tid = threadIdx.x;
    const int w = tid >> 6, l = tid & 63;
    const int l15 = l & 15, lq = l >> 4;
    const int base = blockIdx.x * 32;

#pragma unroll
    for (int i = 0; i < 4; ++i) {
        int chunk = tid + 512 * i;
        int row = chunk >> 6, kc = chunk & 63;
        int grow = base + row;
        float4 v = make_float4(0.f, 0.f, 0.f, 0.f);
        if (grow < NN) v = *(const float4*)(h + (size_t)grow * 256 + kc * 4);
        ushort4 bv = make_ushort4(f2bf(v.x), f2bf(v.y), f2bf(v.z), f2bf(v.w));
        int off = (row * 512 + kc * 8) ^ ((row & 7) << 4);
        *(ushort4*)(smem + off) = bv;
    }
    __syncthreads();

    const int jb = w * 16 + l15;
    short8 bf[8];
#pragma unroll
    for (int kt = 0; kt < 8; ++kt)
        bf[kt] = *(const short8*)((const unsigned char*)Wpt + jb * 512 + kt * 64 + lq * 16);

    f32x4 acc[2];
    acc[0] = (f32x4){0.f, 0.f, 0.f, 0.f};
    acc[1] = (f32x4){0.f, 0.f, 0.f, 0.f};
#pragma unroll
    for (int kt = 0; kt < 8; ++kt) {
#pragma unroll
        for (int rt = 0; rt < 2; ++rt) {
            int arow = rt * 16 + l15;
            int off = (arow * 512 + kt * 64 + lq * 16) ^ ((arow & 7) << 4);
            short8 a = *(const short8*)(smem + off);
            acc[rt] = __builtin_amdgcn_mfma_f32_16x16x32_bf16(a, bf[kt], acc[rt], 0, 0, 0);
        }
    }
#pragma unroll
    for (int rt = 0; rt < 2; ++rt)
#pragma unroll
        for (int r = 0; r < 4; ++r) {
            int row = rt * 16 + lq * 4 + r;
            int grow = base + row;
            if (grow < NN) hp_bf[(size_t)grow * 128 + w * 16 + l15] = f2bf(acc[rt][r]);
        }
}

// ---- K1b: G[r][j][g] = bf16( hp[r] @ W_ih^T (pre-scaled) + bsum ), interleaved 4-gate pack ----
__global__ __launch_bounds__(512, 2) void g_kernel(const unsigned short* __restrict__ hp_bf,
                                                   const unsigned short* __restrict__ Wih_b,
                                                   const float* __restrict__ bsum,
                                                   unsigned short* __restrict__ G) {
    __shared__ __align__(16) unsigned char smem[8192];
    const int tid = threadIdx.x;
    const int w = tid >> 6, l = tid & 63;
    const int l15 = l & 15, lq = l >> 4;
    const int base = blockIdx.x * 32;
    const int colj = w * 16 + l15;

    {   // stage 32 hp rows (bf16, swizzled)
        int row = tid >> 4, c = tid & 15;
        int grow = base + row; if (grow >= NN) grow = NN - 1;
        uint4 v = *(const uint4*)((const unsigned char*)hp_bf + (size_t)grow * 256 + c * 16);
        *(uint4*)(smem + ((row * 256 + c * 16) ^ ((row & 7) << 4))) = v;
    }
    __syncthreads();

    short8 bw[4][4];
    float bi[4];
#pragma unroll
    for (int g = 0; g < 4; ++g) {
#pragma unroll
        for (int kt = 0; kt < 4; ++kt)
            bw[g][kt] = *(const short8*)((const unsigned char*)Wih_b + (g * 128 + colj) * 256 + kt * 64 + lq * 16);
        bi[g] = bsum[g * 128 + colj];
    }
    const int off0 = (l15 * 256 + lq * 16) ^ ((l15 & 7) << 4);

    f32x4 acc[4][2];
#pragma unroll
    for (int g = 0; g < 4; ++g) { acc[g][0] = (f32x4){bi[g], bi[g], bi[g], bi[g]}; acc[g][1] = acc[g][0]; }
#pragma unroll
    for (int kt = 0; kt < 4; ++kt)
#pragma unroll
        for (int rt = 0; rt < 2; ++rt) {
            short8 a = *(const short8*)(smem + rt * 4096 + (off0 ^ (kt << 6)));
#pragma unroll
            for (int g = 0; g < 4; ++g)
                acc[g][rt] = __builtin_amdgcn_mfma_f32_16x16x32_bf16(a, bw[g][kt], acc[g][rt], 0, 0, 0);
        }
#pragma unroll
    for (int rt = 0; rt < 2; ++rt)
#pragma unroll
        for (int e = 0; e < 4; ++e) {
            int grow = base + rt * 16 + lq * 4 + e;
            if (grow < NN) {
                ushort4 pk = make_ushort4(f2bf(acc[0][rt][e]), f2bf(acc[1][rt][e]),
                                          f2bf(acc[2][rt][e]), f2bf(acc[3][rt][e]));
                *(ushort4*)(G + (size_t)grow * 512 + colj * 4) = pk;
            }
        }
}

// ---- K2: LSTM recurrence with precomputed gate-x (G gather -> acc C-layout).
// 32 rows/block, 8 waves; wave w = all 4 gates for cols w*16..+15 (W_hh only: 64 regs).
// Per step: acc = unpack(gx) ; h-GEMM (32 MFMA) ; prefetch G(t+1)/idx(t+2) ;
//           update (trans) -> h -> hbuf[np] ; ONE barrier (h ping-pong).
// LDS (24KB): hbuf0 @0, hbuf1 @8192, hpbuf @16384
template<int RP>
__device__ __forceinline__ void lstm_step(unsigned char* lds, int t,
    uint2 (&gx)[2][8], int (&idx)[2][8], const int (&aoff)[8],
    const short8 (&bw)[4][4], f32x4 (&cst)[2],
    const unsigned char* Gp, const int* __restrict__ agg,
    const int off0, const int colj, const int lq, const int base,
    float* __restrict__ out)
{
    constexpr int NP = RP ^ 1;
    f32x4 acc[4][2];
#pragma unroll
    for (int rt = 0; rt < 2; ++rt)
#pragma unroll
        for (int e = 0; e < 4; ++e) {
            uint2 u = gx[RP][rt * 4 + e];
            acc[0][rt][e] = __uint_as_float(u.x << 16);
            acc[1][rt][e] = __uint_as_float(u.x & 0xFFFF0000u);
            acc[2][rt][e] = __uint_as_float(u.y << 16);
            acc[3][rt][e] = __uint_as_float(u.y & 0xFFFF0000u);
        }
    if (t > 0) {  // h-GEMM: acc += h_t @ W_hh
        __builtin_amdgcn_s_setprio(1);
#pragma unroll
        for (int kt = 0; kt < 4; ++kt)
#pragma unroll
            for (int rt = 0; rt < 2; ++rt) {
                short8 a = *(const short8*)(lds + (RP << 13) + rt * 4096 + (off0 ^ (kt << 6)));
#pragma unroll
                for (int g = 0; g < 4; ++g)
                    acc[g][rt] = __builtin_amdgcn_mfma_f32_16x16x32_bf16(a, bw[g][kt], acc[g][rt], 0, 0, 0);
            }
        __builtin_amdgcn_s_setprio(0);
    }
    if (t <= 18) {  // prefetch G(t+1) (idx loaded last step)
#pragma unroll
        for (int k = 0; k < 8; ++k)
            gx[NP][k] = *(const uint2*)(Gp + (size_t)idx[NP][k] * 1024 + colj * 8);
    }
    if (t <= 17) {  // prefetch idx(t+2) into freed slot
#pragma unroll
        for (int k = 0; k < 8; ++k) idx[RP][k] = agg[aoff[k] + t + 2];
    }
    // cell update -> h(t+1) into hbuf[NP]
#pragma unroll
    for (int rt = 0; rt < 2; ++rt)
#pragma unroll
        for (int e = 0; e < 4; ++e) {
            float c = fmaf(sigp(acc[1][rt][e]), cst[rt][e], sigp(acc[0][rt][e]) * tanhp(acc[2][rt][e]));
            cst[rt][e] = c;
            float hv = sigp(acc[3][rt][e]) * tanhp((2.f * L2E) * c);
            unsigned pk;
            asm("v_cvt_pk_bf16_f32 %0, %1, %2" : "=v"(pk) : "v"(hv), "v"(hv));
            int row = rt * 16 + lq * 4 + e;
            *(unsigned short*)(lds + (NP << 13) + ((row * 256 + colj * 2) ^ ((row & 7) << 4))) = (unsigned short)pk;
            if (t == KSEQ - 1) {
                int grow = base + row;
                if (grow < NN) {
                    out[HN_OFF + (size_t)grow * 128 + colj] = hv;
                    out[CN_OFF + (size_t)grow * 128 + colj] = c;
                }
            }
        }
    __syncthreads();  // h(t+1) visible; hbuf[RP] reads all done (write buffer differs)
}

__global__ __launch_bounds__(512, 2) void lstm_kernel(const unsigned short* __restrict__ hp_bf,
                                                      const int* __restrict__ agg,
                                                      const unsigned short* __restrict__ G,
                                                      const unsigned short* __restrict__ Whh_b,
                                                      const unsigned short* __restrict__ Wtt,
                                                      float* __restrict__ out) {
    __shared__ __align__(16) unsigned char lds[24576];
    const int tid = threadIdx.x;
    const int w = tid >> 6, l = tid & 63;
    const int l15 = l & 15, lq = l >> 4;
    const int base = blockIdx.x * 32;
    const int colj = w * 16 + l15;

    {   // stage own hp rows -> hpbuf (persists to epilogue)
        int row = tid >> 4, c = tid & 15;
        int grow = base + row; if (grow >= NN) grow = NN - 1;
        uint4 v = *(const uint4*)((const unsigned char*)hp_bf + (size_t)grow * 256 + c * 16);
        *(uint4*)(lds + 16384 + ((row * 256 + c * 16) ^ ((row & 7) << 4))) = v;
    }

    // W_hh fragments: 4 gates x 4 k-tiles (K=128) -> 64 regs
    short8 bw[4][4];
#pragma unroll
    for (int g = 0; g < 4; ++g)
#pragma unroll
        for (int kt = 0; kt < 4; ++kt)
            bw[g][kt] = *(const short8*)((const unsigned char*)Whh_b + (g * 128 + colj) * 256 + kt * 64 + lq * 16);

    const int off0 = (l15 * 256 + lq * 16) ^ ((l15 & 7) << 4);
    const unsigned char* Gp = (const unsigned char*)G;

    // per-lane agg row offsets for rows rt*16 + lq*4 + e
    int aoff[8];
#pragma unroll
    for (int rt = 0; rt < 2; ++rt)
#pragma unroll
        for (int e = 0; e < 4; ++e) {
            int grow = base + rt * 16 + lq * 4 + e;
            if (grow >= NN) grow = NN - 1;
            aoff[rt * 4 + e] = grow * KSEQ;
        }

    int idx[2][8];
    uint2 gx[2][8];
#pragma unroll
    for (int k = 0; k < 8; ++k) idx[0][k] = agg[aoff[k] + 0];
#pragma unroll
    for (int k = 0; k < 8; ++k) gx[0][k] = *(const uint2*)(Gp + (size_t)idx[0][k] * 1024 + colj * 8);
#pragma unroll
    for (int k = 0; k < 8; ++k) idx[1][k] = agg[aoff[k] + 1];

    f32x4 cst[2];
    cst[0] = (f32x4){0.f, 0.f, 0.f, 0.f};
    cst[1] = cst[0];
    __syncthreads();  // hpbuf staged

#pragma unroll 1
    for (int tt = 0; tt < KSEQ; tt += 2) {
        lstm_step<0>(lds, tt,     gx, idx, aoff, bw, cst, Gp, agg, off0, colj, lq, base, out);
        lstm_step<1>(lds, tt + 1, gx, idx, aoff, bw, cst, Gp, agg, off0, colj, lq, base, out);
    }
    // hbuf0 = h_20 (written at t=19 -> NP=0); hpbuf = own hp rows

    // epilogue: out = elu([hp | h_n] @ W)
    short8 bo[8];
#pragma unroll
    for (int kt = 0; kt < 8; ++kt)
        bo[kt] = *(const short8*)((const unsigned char*)Wtt + colj * 512 + kt * 64 + lq * 16);

    f32x4 a2[2];
    a2[0] = (f32x4){0.f, 0.f, 0.f, 0.f};
    a2[1] = a2[0];
#pragma unroll
    for (int kt = 0; kt < 4; ++kt)
#pragma unroll
        for (int rt = 0; rt < 2; ++rt) {
            short8 a = *(const short8*)(lds + 16384 + rt * 4096 + (off0 ^ (kt << 6)));  // hp
            a2[rt] = __builtin_amdgcn_mfma_f32_16x16x32_bf16(a, bo[kt], a2[rt], 0, 0, 0);
        }
#pragma unroll
    for (int kt = 0; kt < 4; ++kt)
#pragma unroll
        for (int rt = 0; rt < 2; ++rt) {
            short8 a = *(const short8*)(lds + rt * 4096 + (off0 ^ (kt << 6)));           // h_n (hbuf0)
            a2[rt] = __builtin_amdgcn_mfma_f32_16x16x32_bf16(a, bo[kt + 4], a2[rt], 0, 0, 0);
        }
#pragma unroll
    for (int rt = 0; rt < 2; ++rt)
#pragma unroll
        for (int e = 0; e < 4; ++e) {
            int grow = base + rt * 16 + lq * 4 + e;
            if (grow < NN) {
                float v = a2[rt][e];
                out[(size_t)grow * 128 + colj] = (v > 0.f) ? v : (exp2x(L2E * v) - 1.f);
            }
        }
}

extern "C" void kernel_launch(void* const* d_in, const int* in_sizes, int n_in,
                              void* d_out, int out_size, void* d_ws, size_t ws_size,
                              hipStream_t stream) {
    (void)in_sizes; (void)n_in; (void)out_size; (void)ws_size;
    const float* h   = (const float*)d_in[0];
    const int*   agg = (const int*)d_in[1];
    const float* Wp  = (const float*)d_in[2];
    const float* W   = (const float*)d_in[3];
    const float* Wih = (const float*)d_in[4];
    const float* Whh = (const float*)d_in[5];
    const float* bih = (const float*)d_in[6];
    const float* bhh = (const float*)d_in[7];
    float* out = (float*)d_out;

    unsigned short* hp_bf = (unsigned short*)d_ws;       // 50000*128 bf16 (12.8MB)
    unsigned short* G     = hp_bf + 6400000;             // 50000*512 bf16 (51.2MB)
    unsigned short* Wih_b = G + 25600000;                // 512*128 (pre-scaled)
    unsigned short* Whh_b = Wih_b + 65536;               // 512*128 (pre-scaled)
    unsigned short* Wpt   = Whh_b + 65536;               // 128*256 (W_past^T)
    unsigned short* Wtt   = Wpt + 32768;                 // 128*256 (W^T)
    float*          bsum  = (float*)(Wtt + 32768);       // 512 (pre-scaled)

    prep_kernel<<<771, 256, 0, stream>>>(Wp, W, Wih, Whh, bih, bhh, Wih_b, Whh_b, Wpt, Wtt, bsum);
    hp_kernel<<<1563, 512, 0, stream>>>(h, Wpt, hp_bf);
    g_kernel<<<1563, 512, 0, stream>>>(hp_bf, Wih_b, bsum, G);
    lstm_kernel<<<1563, 512, 0, stream>>>(hp_bf, agg, G, Whh_b, Wtt, out);
}

// Round 10
// 334.351 us; speedup vs baseline: 3.0193x; 1.1456x over previous
//
#include <hip/hip_runtime.h>

#define NN 50000
#define KSEQ 20
#define HN_OFF 6400000   // N*128
#define CN_OFF 12800000  // 2*N*128

using short8 = __attribute__((ext_vector_type(8))) short;
using f32x4  = __attribute__((ext_vector_type(4))) float;

__device__ __forceinline__ unsigned short f2bf(float f) {
    unsigned int u = __float_as_uint(f);
    return (unsigned short)((u + 0x7FFFu + ((u >> 16) & 1u)) >> 16);  // RNE
}
__device__ __forceinline__ float exp2x(float x) { float r; asm("v_exp_f32 %0, %1" : "=v"(r) : "v"(x)); return r; }
__device__ __forceinline__ float rcpx(float x)  { float r; asm("v_rcp_f32 %0, %1" : "=v"(r) : "v"(x)); return r; }

#define L2E 1.4426950408889634f
// gate pre-activations arrive PRE-SCALED (i,f,o by -l2e; g by +2*l2e)
__device__ __forceinline__ float sigp(float y)  { return rcpx(1.f + exp2x(y)); }
__device__ __forceinline__ float tanhp(float y) { return fmaf(-2.f, rcpx(1.f + exp2x(y)), 1.f); }

// ---- prep: bf16 weight packs (pre-scaled LSTM weights, transposes, bias sum) ----
__global__ void prep_kernel(const float* __restrict__ Wp, const float* __restrict__ W,
                            const float* __restrict__ Wih, const float* __restrict__ Whh,
                            const float* __restrict__ bih, const float* __restrict__ bhh,
                            unsigned short* __restrict__ Wih_b, unsigned short* __restrict__ Whh_b,
                            unsigned short* __restrict__ Wpt, unsigned short* __restrict__ Wtt,
                            float* __restrict__ bsum) {
    int tid = blockIdx.x * blockDim.x + threadIdx.x;
    if (tid < 65536) {  // gate scale: i,f,o -> -l2e ; g -> +2*l2e
        float sc = ((tid >> 14) == 2) ? (2.f * L2E) : (-L2E);
        Wih_b[tid] = f2bf(Wih[tid] * sc); return;
    }
    tid -= 65536;
    if (tid < 65536) {
        float sc = ((tid >> 14) == 2) ? (2.f * L2E) : (-L2E);
        Whh_b[tid] = f2bf(Whh[tid] * sc); return;
    }
    tid -= 65536;
    if (tid < 32768) { int j = tid >> 8, k = tid & 255; Wpt[tid] = f2bf(Wp[k * 128 + j]); return; }
    tid -= 32768;
    if (tid < 32768) { int j = tid >> 8, k = tid & 255; Wtt[tid] = f2bf(W[k * 128 + j]); return; }
    tid -= 32768;
    if (tid < 512) {
        float sc = ((tid >> 7) == 2) ? (2.f * L2E) : (-L2E);
        bsum[tid] = (bih[tid] + bhh[tid]) * sc;
    }
}

// ---- K1: hp = bf16(h @ W_past), 32 rows/block, 8 waves (16 cols each) ----
__global__ __launch_bounds__(512, 2) void hp_kernel(const float* __restrict__ h,
                                                    const unsigned short* __restrict__ Wpt,
                                                    unsigned short* __restrict__ hp_bf) {
    __shared__ __align__(16) unsigned char smem[32 * 512];
    const int tid = threadIdx.x;
    const int w = tid >> 6, l = tid & 63;
    const int l15 = l & 15, lq = l >> 4;
    const int base = blockIdx.x * 32;

#pragma unroll
    for (int i = 0; i < 4; ++i) {
        int chunk = tid + 512 * i;
        int row = chunk >> 6, kc = chunk & 63;
        int grow = base + row;
        float4 v = make_float4(0.f, 0.f, 0.f, 0.f);
        if (grow < NN) v = *(const float4*)(h + (size_t)grow * 256 + kc * 4);
        ushort4 bv = make_ushort4(f2bf(v.x), f2bf(v.y), f2bf(v.z), f2bf(v.w));
        int off = (row * 512 + kc * 8) ^ ((row & 7) << 4);
        *(ushort4*)(smem + off) = bv;
    }
    __syncthreads();

    const int jb = w * 16 + l15;
    short8 bf[8];
#pragma unroll
    for (int kt = 0; kt < 8; ++kt)
        bf[kt] = *(const short8*)((const unsigned char*)Wpt + jb * 512 + kt * 64 + lq * 16);

    f32x4 acc[2];
    acc[0] = (f32x4){0.f, 0.f, 0.f, 0.f};
    acc[1] = (f32x4){0.f, 0.f, 0.f, 0.f};
#pragma unroll
    for (int kt = 0; kt < 8; ++kt) {
#pragma unroll
        for (int rt = 0; rt < 2; ++rt) {
            int arow = rt * 16 + l15;
            int off = (arow * 512 + kt * 64 + lq * 16) ^ ((arow & 7) << 4);
            short8 a = *(const short8*)(smem + off);
            acc[rt] = __builtin_amdgcn_mfma_f32_16x16x32_bf16(a, bf[kt], acc[rt], 0, 0, 0);
        }
    }
#pragma unroll
    for (int rt = 0; rt < 2; ++rt)
#pragma unroll
        for (int r = 0; r < 4; ++r) {
            int row = rt * 16 + lq * 4 + r;
            int grow = base + row;
            if (grow < NN) hp_bf[(size_t)grow * 128 + w * 16 + l15] = f2bf(acc[rt][r]);
        }
}

// ---- K1b: G[r][j][g] = bf16( hp[r] @ W_ih^T (pre-scaled) + bsum ), 4-gate interleave ----
__global__ __launch_bounds__(512, 2) void g_kernel(const unsigned short* __restrict__ hp_bf,
                                                   const unsigned short* __restrict__ Wih_b,
                                                   const float* __restrict__ bsum,
                                                   unsigned short* __restrict__ G) {
    __shared__ __align__(16) unsigned char smem[8192];
    const int tid = threadIdx.x;
    const int w = tid >> 6, l = tid & 63;
    const int l15 = l & 15, lq = l >> 4;
    const int base = blockIdx.x * 32;
    const int colj = w * 16 + l15;

    {   // stage 32 hp rows (bf16, swizzled)
        int row = tid >> 4, c = tid & 15;
        int grow = base + row; if (grow >= NN) grow = NN - 1;
        uint4 v = *(const uint4*)((const unsigned char*)hp_bf + (size_t)grow * 256 + c * 16);
        *(uint4*)(smem + ((row * 256 + c * 16) ^ ((row & 7) << 4))) = v;
    }
    __syncthreads();

    short8 bw[4][4];
    float bi[4];
#pragma unroll
    for (int g = 0; g < 4; ++g) {
#pragma unroll
        for (int kt = 0; kt < 4; ++kt)
            bw[g][kt] = *(const short8*)((const unsigned char*)Wih_b + (g * 128 + colj) * 256 + kt * 64 + lq * 16);
        bi[g] = bsum[g * 128 + colj];
    }
    const int off0 = (l15 * 256 + lq * 16) ^ ((l15 & 7) << 4);

    f32x4 acc[4][2];
#pragma unroll
    for (int g = 0; g < 4; ++g) { acc[g][0] = (f32x4){bi[g], bi[g], bi[g], bi[g]}; acc[g][1] = acc[g][0]; }
#pragma unroll
    for (int kt = 0; kt < 4; ++kt)
#pragma unroll
        for (int rt = 0; rt < 2; ++rt) {
            short8 a = *(const short8*)(smem + rt * 4096 + (off0 ^ (kt << 6)));
#pragma unroll
            for (int g = 0; g < 4; ++g)
                acc[g][rt] = __builtin_amdgcn_mfma_f32_16x16x32_bf16(a, bw[g][kt], acc[g][rt], 0, 0, 0);
        }
#pragma unroll
    for (int rt = 0; rt < 2; ++rt)
#pragma unroll
        for (int e = 0; e < 4; ++e) {
            int grow = base + rt * 16 + lq * 4 + e;
            if (grow < NN) {
                ushort4 pk = make_ushort4(f2bf(acc[0][rt][e]), f2bf(acc[1][rt][e]),
                                          f2bf(acc[2][rt][e]), f2bf(acc[3][rt][e]));
                *(ushort4*)(G + (size_t)grow * 512 + colj * 4) = pk;
            }
        }
}

// ---- K2: LSTM recurrence, 16 rows/block, 8 waves, 2 blocks/CU target.
// Wave w = all 4 gates for cols w*16..+15 (W_hh = 64 regs, AGPR).
// Per step: acc = unpack(gx) ; h-GEMM (16 MFMA) ; load idx(t+1)+gx(t+1) in place ;
//           cell update -> h -> hbuf[NP] ; ONE barrier.
// LDS (12KB): hbuf0 @0, hbuf1 @4096, hpbuf @8192.  50000 = 16*3125 -> no tail.
template<int RP>
__device__ __forceinline__ void lstm_step(unsigned char* lds, int t,
    uint2 (&gx)[4], const short8 (&bw)[4][4], f32x4& cst,
    const unsigned char* Gp, const int* __restrict__ aggrow,
    const int off0, const int colj, const int lq, const int hwb, const int hswz,
    const int base, float* __restrict__ out)
{
    constexpr int NP = RP ^ 1;
    f32x4 acc[4];
#pragma unroll
    for (int e = 0; e < 4; ++e) {
        uint2 u = gx[e];
        acc[0][e] = __uint_as_float(u.x << 16);
        acc[1][e] = __uint_as_float(u.x & 0xFFFF0000u);
        acc[2][e] = __uint_as_float(u.y << 16);
        acc[3][e] = __uint_as_float(u.y & 0xFFFF0000u);
    }
    if (t > 0) {  // h-GEMM: acc += h_t @ W_hh
        __builtin_amdgcn_s_setprio(1);
#pragma unroll
        for (int kt = 0; kt < 4; ++kt) {
            short8 a = *(const short8*)(lds + RP * 4096 + (off0 ^ (kt << 6)));
#pragma unroll
            for (int g = 0; g < 4; ++g)
                acc[g] = __builtin_amdgcn_mfma_f32_16x16x32_bf16(a, bw[g][kt], acc[g], 0, 0, 0);
        }
        __builtin_amdgcn_s_setprio(0);
    }
    if (t <= 18) {  // idx(t+1) then gx(t+1), reusing gx regs (consumed above)
        int i0 = aggrow[0 * KSEQ + t + 1];
        int i1 = aggrow[1 * KSEQ + t + 1];
        int i2 = aggrow[2 * KSEQ + t + 1];
        int i3 = aggrow[3 * KSEQ + t + 1];
        gx[0] = *(const uint2*)(Gp + (size_t)i0 * 1024 + colj * 8);
        gx[1] = *(const uint2*)(Gp + (size_t)i1 * 1024 + colj * 8);
        gx[2] = *(const uint2*)(Gp + (size_t)i2 * 1024 + colj * 8);
        gx[3] = *(const uint2*)(Gp + (size_t)i3 * 1024 + colj * 8);
    }
    // cell update -> h(t+1) into hbuf[NP]
#pragma unroll
    for (int e = 0; e < 4; ++e) {
        float c = fmaf(sigp(acc[1][e]), cst[e], sigp(acc[0][e]) * tanhp(acc[2][e]));
        cst[e] = c;
        float hv = sigp(acc[3][e]) * tanhp((2.f * L2E) * c);
        unsigned pk;
        asm("v_cvt_pk_bf16_f32 %0, %1, %2" : "=v"(pk) : "v"(hv), "v"(hv));
        *(unsigned short*)(lds + NP * 4096 + (((hwb + e * 256) ^ (hswz ^ (e << 4))))) = (unsigned short)pk;
        if (t == KSEQ - 1) {
            int grow = base + lq * 4 + e;   // no tail: always < NN
            out[HN_OFF + (size_t)grow * 128 + colj] = hv;
            out[CN_OFF + (size_t)grow * 128 + colj] = c;
        }
    }
    __syncthreads();  // h(t+1) visible; hbuf[RP] reads done (write buffer differs)
}

__global__ __launch_bounds__(512, 4) void lstm_kernel(const unsigned short* __restrict__ hp_bf,
                                                      const int* __restrict__ agg,
                                                      const unsigned short* __restrict__ G,
                                                      const unsigned short* __restrict__ Whh_b,
                                                      const unsigned short* __restrict__ Wtt,
                                                      float* __restrict__ out) {
    __shared__ __align__(16) unsigned char lds[12288];
    const int tid = threadIdx.x;
    const int w = tid >> 6, l = tid & 63;
    const int l15 = l & 15, lq = l >> 4;
    const int base = blockIdx.x * 16;
    const int colj = w * 16 + l15;

    if (tid < 256) {   // stage own 16 hp rows -> hpbuf @8192 (persists to epilogue)
        int row = tid >> 4, c = tid & 15;
        uint4 v = *(const uint4*)((const unsigned char*)hp_bf + (size_t)(base + row) * 256 + c * 16);
        *(uint4*)(lds + 8192 + ((row * 256 + c * 16) ^ ((row & 7) << 4))) = v;
    }

    // W_hh fragments: 4 gates x 4 k-tiles (K=128) -> 64 regs (AGPR)
    short8 bw[4][4];
#pragma unroll
    for (int g = 0; g < 4; ++g)
#pragma unroll
        for (int kt = 0; kt < 4; ++kt)
            bw[g][kt] = *(const short8*)((const unsigned char*)Whh_b + (g * 128 + colj) * 256 + kt * 64 + lq * 16);

    const int off0 = (l15 * 256 + lq * 16) ^ ((l15 & 7) << 4);
    const int hwb = lq * 1024 + colj * 2;
    const int hswz = (lq & 1) << 6;
    const unsigned char* Gp = (const unsigned char*)G;
    const int* aggrow = agg + (size_t)(base + lq * 4) * KSEQ;   // rows lq*4 + e

    uint2 gx[4];
    {   // gx(0)
        int i0 = aggrow[0], i1 = aggrow[KSEQ], i2 = aggrow[2 * KSEQ], i3 = aggrow[3 * KSEQ];
        gx[0] = *(const uint2*)(Gp + (size_t)i0 * 1024 + colj * 8);
        gx[1] = *(const uint2*)(Gp + (size_t)i1 * 1024 + colj * 8);
        gx[2] = *(const uint2*)(Gp + (size_t)i2 * 1024 + colj * 8);
        gx[3] = *(const uint2*)(Gp + (size_t)i3 * 1024 + colj * 8);
    }
    f32x4 cst = (f32x4){0.f, 0.f, 0.f, 0.f};
    __syncthreads();  // hpbuf staged

#pragma unroll 1
    for (int tt = 0; tt < KSEQ; tt += 2) {
        lstm_step<0>(lds, tt,     gx, bw, cst, Gp, aggrow, off0, colj, lq, hwb, hswz, base, out);
        lstm_step<1>(lds, tt + 1, gx, bw, cst, Gp, aggrow, off0, colj, lq, hwb, hswz, base, out);
    }
    // hbuf0 = h_20 (t=19 wrote NP=0); hpbuf @8192 = own hp rows

    // epilogue: out = elu([hp | h_n] @ W); wave w -> out-cols colj, 16 rows
    short8 bo[8];
#pragma unroll
    for (int kt = 0; kt < 8; ++kt)
        bo[kt] = *(const short8*)((const unsigned char*)Wtt + colj * 512 + kt * 64 + lq * 16);

    f32x4 a2 = (f32x4){0.f, 0.f, 0.f, 0.f};
#pragma unroll
    for (int kt = 0; kt < 4; ++kt) {
        short8 a = *(const short8*)(lds + 8192 + (off0 ^ (kt << 6)));   // hp
        a2 = __builtin_amdgcn_mfma_f32_16x16x32_bf16(a, bo[kt], a2, 0, 0, 0);
    }
#pragma unroll
    for (int kt = 0; kt < 4; ++kt) {
        short8 a = *(const short8*)(lds + (off0 ^ (kt << 6)));          // h_n (hbuf0)
        a2 = __builtin_amdgcn_mfma_f32_16x16x32_bf16(a, bo[kt + 4], a2, 0, 0, 0);
    }
#pragma unroll
    for (int e = 0; e < 4; ++e) {
        int grow = base + lq * 4 + e;
        float v = a2[e];
        out[(size_t)grow * 128 + colj] = (v > 0.f) ? v : (exp2x(L2E * v) - 1.f);
    }
}

extern "C" void kernel_launch(void* const* d_in, const int* in_sizes, int n_in,
                              void* d_out, int out_size, void* d_ws, size_t ws_size,
                              hipStream_t stream) {
    (void)in_sizes; (void)n_in; (void)out_size; (void)ws_size;
    const float* h   = (const float*)d_in[0];
    const int*   agg = (const int*)d_in[1];
    const float* Wp  = (const float*)d_in[2];
    const float* W   = (const float*)d_in[3];
    const float* Wih = (const float*)d_in[4];
    const float* Whh = (const float*)d_in[5];
    const float* bih = (const float*)d_in[6];
    const float* bhh = (const float*)d_in[7];
    float* out = (float*)d_out;

    unsigned short* hp_bf = (unsigned short*)d_ws;       // 50000*128 bf16 (12.8MB)
    unsigned short* G     = hp_bf + 6400000;             // 50000*512 bf16 (51.2MB)
    unsigned short* Wih_b = G + 25600000;                // 512*128 (pre-scaled)
    unsigned short* Whh_b = Wih_b + 65536;               // 512*128 (pre-scaled)
    unsigned short* Wpt   = Whh_b + 65536;               // 128*256 (W_past^T)
    unsigned short* Wtt   = Wpt + 32768;                 // 128*256 (W^T)
    float*          bsum  = (float*)(Wtt + 32768);       // 512 (pre-scaled)

    prep_kernel<<<771, 256, 0, stream>>>(Wp, W, Wih, Whh, bih, bhh, Wih_b, Whh_b, Wpt, Wtt, bsum);
    hp_kernel<<<1563, 512, 0, stream>>>(h, Wpt, hp_bf);
    g_kernel<<<1563, 512, 0, stream>>>(hp_bf, Wih_b, bsum, G);
    lstm_kernel<<<3125, 512, 0, stream>>>(hp_bf, agg, G, Whh_b, Wtt, out);
}

// Round 12
// 299.961 us; speedup vs baseline: 3.3654x; 1.1146x over previous
//
#include <hip/hip_runtime.h>

#define NN 50000
#define KSEQ 20
#define HN_OFF 6400000   // N*128
#define CN_OFF 12800000  // 2*N*128

using short8 = __attribute__((ext_vector_type(8))) short;
using f32x4  = __attribute__((ext_vector_type(4))) float;

__device__ __forceinline__ unsigned short f2bf(float f) {
    unsigned int u = __float_as_uint(f);
    return (unsigned short)((u + 0x7FFFu + ((u >> 16) & 1u)) >> 16);  // RNE
}
__device__ __forceinline__ float exp2x(float x) { float r; asm("v_exp_f32 %0, %1" : "=v"(r) : "v"(x)); return r; }
__device__ __forceinline__ float rcpx(float x)  { float r; asm("v_rcp_f32 %0, %1" : "=v"(r) : "v"(x)); return r; }

#define L2E 1.4426950408889634f
// gate pre-activations arrive PRE-SCALED (i,f,o by -l2e; g by +2*l2e)
__device__ __forceinline__ float sigp(float y)  { return rcpx(1.f + exp2x(y)); }
__device__ __forceinline__ float tanhp(float y) { return fmaf(-2.f, rcpx(1.f + exp2x(y)), 1.f); }

// ---- prep: bf16 weight packs (pre-scaled LSTM weights, transposes, bias sum) ----
__global__ void prep_kernel(const float* __restrict__ Wp, const float* __restrict__ W,
                            const float* __restrict__ Wih, const float* __restrict__ Whh,
                            const float* __restrict__ bih, const float* __restrict__ bhh,
                            unsigned short* __restrict__ Wih_b, unsigned short* __restrict__ Whh_b,
                            unsigned short* __restrict__ Wpt, unsigned short* __restrict__ Wtt,
                            float* __restrict__ bsum) {
    int tid = blockIdx.x * blockDim.x + threadIdx.x;
    if (tid < 65536) {  // gate scale: i,f,o -> -l2e ; g -> +2*l2e
        float sc = ((tid >> 14) == 2) ? (2.f * L2E) : (-L2E);
        Wih_b[tid] = f2bf(Wih[tid] * sc); return;
    }
    tid -= 65536;
    if (tid < 65536) {
        float sc = ((tid >> 14) == 2) ? (2.f * L2E) : (-L2E);
        Whh_b[tid] = f2bf(Whh[tid] * sc); return;
    }
    tid -= 65536;
    if (tid < 32768) { int j = tid >> 8, k = tid & 255; Wpt[tid] = f2bf(Wp[k * 128 + j]); return; }
    tid -= 32768;
    if (tid < 32768) { int j = tid >> 8, k = tid & 255; Wtt[tid] = f2bf(W[k * 128 + j]); return; }
    tid -= 32768;
    if (tid < 512) {
        float sc = ((tid >> 7) == 2) ? (2.f * L2E) : (-L2E);
        bsum[tid] = (bih[tid] + bhh[tid]) * sc;
    }
}

// ---- K1 (fused): hp = bf16(h @ W_past) -> global + LDS; G = bf16(hp @ W_ih^T + b)
// 32 rows/block, 8 waves (16 cols each).
__global__ __launch_bounds__(512, 2) void hp_g_kernel(const float* __restrict__ h,
                                                      const unsigned short* __restrict__ Wpt,
                                                      const unsigned short* __restrict__ Wih_b,
                                                      const float* __restrict__ bsum,
                                                      unsigned short* __restrict__ hp_bf,
                                                      unsigned short* __restrict__ G) {
    __shared__ __align__(16) unsigned char smem[24576];   // hstage 16KB @0, hpstage 8KB @16384
    const int tid = threadIdx.x;
    const int w = tid >> 6, l = tid & 63;
    const int l15 = l & 15, lq = l >> 4;
    const int base = blockIdx.x * 32;
    const int colj = w * 16 + l15;

    // stage h rows -> bf16 (32 rows x 512B, swizzled)
#pragma unroll
    for (int i = 0; i < 4; ++i) {
        int chunk = tid + 512 * i;
        int row = chunk >> 6, kc = chunk & 63;
        int grow = base + row;
        float4 v = make_float4(0.f, 0.f, 0.f, 0.f);
        if (grow < NN) v = *(const float4*)(h + (size_t)grow * 256 + kc * 4);
        ushort4 bv = make_ushort4(f2bf(v.x), f2bf(v.y), f2bf(v.z), f2bf(v.w));
        int off = (row * 512 + kc * 8) ^ ((row & 7) << 4);
        *(ushort4*)(smem + off) = bv;
    }
    __syncthreads();

    // ---- hp GEMM ----
    short8 bf[8];
#pragma unroll
    for (int kt = 0; kt < 8; ++kt)
        bf[kt] = *(const short8*)((const unsigned char*)Wpt + colj * 512 + kt * 64 + lq * 16);

    f32x4 acc[2];
    acc[0] = (f32x4){0.f, 0.f, 0.f, 0.f};
    acc[1] = acc[0];
#pragma unroll
    for (int kt = 0; kt < 8; ++kt) {
#pragma unroll
        for (int rt = 0; rt < 2; ++rt) {
            int arow = rt * 16 + l15;
            int off = (arow * 512 + kt * 64 + lq * 16) ^ ((arow & 7) << 4);
            short8 a = *(const short8*)(smem + off);
            acc[rt] = __builtin_amdgcn_mfma_f32_16x16x32_bf16(a, bf[kt], acc[rt], 0, 0, 0);
        }
    }
    // write hp to global + LDS (bf16)
#pragma unroll
    for (int rt = 0; rt < 2; ++rt)
#pragma unroll
        for (int r = 0; r < 4; ++r) {
            int row = rt * 16 + lq * 4 + r;
            int grow = base + row;
            unsigned short hb = f2bf(acc[rt][r]);
            if (grow < NN) hp_bf[(size_t)grow * 128 + colj] = hb;
            *(unsigned short*)(smem + 16384 + ((row * 256 + colj * 2) ^ ((row & 7) << 4))) = hb;
        }
    __syncthreads();

    // ---- G GEMM: 4 gates, K=128 from hpstage ----
    short8 bw4[4][4];
    float bi[4];
#pragma unroll
    for (int g = 0; g < 4; ++g) {
#pragma unroll
        for (int kt = 0; kt < 4; ++kt)
            bw4[g][kt] = *(const short8*)((const unsigned char*)Wih_b + (g * 128 + colj) * 256 + kt * 64 + lq * 16);
        bi[g] = bsum[g * 128 + colj];
    }
    const int off0 = (l15 * 256 + lq * 16) ^ ((l15 & 7) << 4);

    f32x4 ag[4][2];
#pragma unroll
    for (int g = 0; g < 4; ++g) { ag[g][0] = (f32x4){bi[g], bi[g], bi[g], bi[g]}; ag[g][1] = ag[g][0]; }
#pragma unroll
    for (int kt = 0; kt < 4; ++kt)
#pragma unroll
        for (int rt = 0; rt < 2; ++rt) {
            short8 a = *(const short8*)(smem + 16384 + rt * 4096 + (off0 ^ (kt << 6)));
#pragma unroll
            for (int g = 0; g < 4; ++g)
                ag[g][rt] = __builtin_amdgcn_mfma_f32_16x16x32_bf16(a, bw4[g][kt], ag[g][rt], 0, 0, 0);
        }
#pragma unroll
    for (int rt = 0; rt < 2; ++rt)
#pragma unroll
        for (int e = 0; e < 4; ++e) {
            int grow = base + rt * 16 + lq * 4 + e;
            if (grow < NN) {
                ushort4 pk = make_ushort4(f2bf(ag[0][rt][e]), f2bf(ag[1][rt][e]),
                                          f2bf(ag[2][rt][e]), f2bf(ag[3][rt][e]));
                *(ushort4*)(G + (size_t)grow * 512 + colj * 4) = pk;
            }
        }
}

// ---- K2: LSTM recurrence, 16 rows/block, 8 waves, 2 blocks/CU.
// Wave w = all 4 gates for cols w*16..+15 (W_hh = 64 regs, AGPR).
// gx prefetch distance 2 (parity buffers); idx slab staged in LDS (no in-loop idx VMEM).
// LDS (14KB): hbuf0 @0, hbuf1 @4096, hpbuf @8192, aggbuf @12288 (1280B).
template<int RP>
__device__ __forceinline__ void lstm_step(unsigned char* lds, int t,
    uint2 (&gx)[2][4], const short8 (&bw)[4][4], f32x4& cst,
    const unsigned char* Gp, const unsigned cb,
    const int off0, const int colj, const int lq, const int hwb, const int hswz,
    const int base, float* __restrict__ out)
{
    constexpr int NP = RP ^ 1;
    f32x4 acc[4];
#pragma unroll
    for (int e = 0; e < 4; ++e) {
        uint2 u = gx[RP][e];
        acc[0][e] = __uint_as_float(u.x << 16);
        acc[1][e] = __uint_as_float(u.x & 0xFFFF0000u);
        acc[2][e] = __uint_as_float(u.y << 16);
        acc[3][e] = __uint_as_float(u.y & 0xFFFF0000u);
    }
    if (t > 0) {  // h-GEMM: acc += h_t @ W_hh
        __builtin_amdgcn_s_setprio(1);
#pragma unroll
        for (int kt = 0; kt < 4; ++kt) {
            short8 a = *(const short8*)(lds + RP * 4096 + (off0 ^ (kt << 6)));
#pragma unroll
            for (int g = 0; g < 4; ++g)
                acc[g] = __builtin_amdgcn_mfma_f32_16x16x32_bf16(a, bw[g][kt], acc[g], 0, 0, 0);
        }
        __builtin_amdgcn_s_setprio(0);
    }
    if (t <= 17) {  // gx(t+2) into just-consumed buffer; idx from LDS slab
#pragma unroll
        for (int e = 0; e < 4; ++e) {
            int idx = *(const int*)(lds + 12288 + (lq * 4 + e) * 80 + (t + 2) * 4);
            gx[RP][e] = *(const uint2*)(Gp + (((unsigned)idx << 10) + cb));
        }
    }
    // cell update -> h(t+1) into hbuf[NP]
#pragma unroll
    for (int e = 0; e < 4; ++e) {
        float c = fmaf(sigp(acc[1][e]), cst[e], sigp(acc[0][e]) * tanhp(acc[2][e]));
        cst[e] = c;
        float hv = sigp(acc[3][e]) * tanhp((2.f * L2E) * c);
        unsigned pk;
        asm("v_cvt_pk_bf16_f32 %0, %1, %2" : "=v"(pk) : "v"(hv), "v"(hv));
        *(unsigned short*)(lds + NP * 4096 + ((hwb + e * 256) ^ (hswz ^ (e << 4)))) = (unsigned short)pk;
        if (t == KSEQ - 1) {
            int grow = base + lq * 4 + e;   // 50000 = 16*3125: no tail
            out[HN_OFF + (size_t)grow * 128 + colj] = hv;
            out[CN_OFF + (size_t)grow * 128 + colj] = c;
        }
    }
    __syncthreads();  // h(t+1) visible; hbuf[RP] reads done (write buffer differs)
}

__global__ __launch_bounds__(512, 4) void lstm_kernel(const unsigned short* __restrict__ hp_bf,
                                                      const int* __restrict__ agg,
                                                      const unsigned short* __restrict__ G,
                                                      const unsigned short* __restrict__ Whh_b,
                                                      const unsigned short* __restrict__ Wtt,
                                                      float* __restrict__ out) {
    __shared__ __align__(16) unsigned char lds[14336];
    const int tid = threadIdx.x;
    const int w = tid >> 6, l = tid & 63;
    const int l15 = l & 15, lq = l >> 4;
    const int base = blockIdx.x * 16;
    const int colj = w * 16 + l15;

    // stage hp rows (@8192, 256 threads) and the 16x20 index slab (@12288, 320 threads)
    if (tid < 256) {
        int row = tid >> 4, c = tid & 15;
        uint4 v = *(const uint4*)((const unsigned char*)hp_bf + (size_t)(base + row) * 256 + c * 16);
        *(uint4*)(lds + 8192 + ((row * 256 + c * 16) ^ ((row & 7) << 4))) = v;
    }
    if (tid < 320) {                               // 320 dwords = 16 rows x 20 t
        *(int*)(lds + 12288 + tid * 4) = agg[(size_t)base * KSEQ + tid];
    }

    // W_hh fragments: 4 gates x 4 k-tiles (K=128) -> 64 regs (AGPR)
    short8 bw[4][4];
#pragma unroll
    for (int g = 0; g < 4; ++g)
#pragma unroll
        for (int kt = 0; kt < 4; ++kt)
            bw[g][kt] = *(const short8*)((const unsigned char*)Whh_b + (g * 128 + colj) * 256 + kt * 64 + lq * 16);

    const int off0 = (l15 * 256 + lq * 16) ^ ((l15 & 7) << 4);
    const int hwb = lq * 1024 + colj * 2;
    const int hswz = (lq & 1) << 6;
    const unsigned char* Gp = (const unsigned char*)G;
    const unsigned cb = (unsigned)colj * 8;        // byte offset within a G row

    f32x4 cst = (f32x4){0.f, 0.f, 0.f, 0.f};
    __syncthreads();  // hpbuf + aggbuf staged

    uint2 gx[2][4];
#pragma unroll
    for (int tp = 0; tp < 2; ++tp)
#pragma unroll
        for (int e = 0; e < 4; ++e) {
            int idx = *(const int*)(lds + 12288 + (lq * 4 + e) * 80 + tp * 4);
            gx[tp][e] = *(const uint2*)(Gp + (((unsigned)idx << 10) + cb));
        }

#pragma unroll 1
    for (int tt = 0; tt < KSEQ; tt += 2) {
        lstm_step<0>(lds, tt,     gx, bw, cst, Gp, cb, off0, colj, lq, hwb, hswz, base, out);
        lstm_step<1>(lds, tt + 1, gx, bw, cst, Gp, cb, off0, colj, lq, hwb, hswz, base, out);
    }
    // hbuf0 = h_20; hpbuf @8192 = own hp rows

    // epilogue: out = elu([hp | h_n] @ W)
    short8 bo[8];
#pragma unroll
    for (int kt = 0; kt < 8; ++kt)
        bo[kt] = *(const short8*)((const unsigned char*)Wtt + colj * 512 + kt * 64 + lq * 16);

    f32x4 a2 = (f32x4){0.f, 0.f, 0.f, 0.f};
#pragma unroll
    for (int kt = 0; kt < 4; ++kt) {
        short8 a = *(const short8*)(lds + 8192 + (off0 ^ (kt << 6)));   // hp
        a2 = __builtin_amdgcn_mfma_f32_16x16x32_bf16(a, bo[kt], a2, 0, 0, 0);
    }
#pragma unroll
    for (int kt = 0; kt < 4; ++kt) {
        short8 a = *(const short8*)(lds + (off0 ^ (kt << 6)));          // h_n (hbuf0)
        a2 = __builtin_amdgcn_mfma_f32_16x16x32_bf16(a, bo[kt + 4], a2, 0, 0, 0);
    }
#pragma unroll
    for (int e = 0; e < 4; ++e) {
        int grow = base + lq * 4 + e;
        float v = a2[e];
        out[(size_t)grow * 128 + colj] = (v > 0.f) ? v : (exp2x(L2E * v) - 1.f);
    }
}

extern "C" void kernel_launch(void* const* d_in, const int* in_sizes, int n_in,
                              void* d_out, int out_size, void* d_ws, size_t ws_size,
                              hipStream_t stream) {
    (void)in_sizes; (void)n_in; (void)out_size; (void)ws_size;
    const float* h   = (const float*)d_in[0];
    const int*   agg = (const int*)d_in[1];
    const float* Wp  = (const float*)d_in[2];
    const float* W   = (const float*)d_in[3];
    const float* Wih = (const float*)d_in[4];
    const float* Whh = (const float*)d_in[5];
    const float* bih = (const float*)d_in[6];
    const float* bhh = (const float*)d_in[7];
    float* out = (float*)d_out;

    unsigned short* hp_bf = (unsigned short*)d_ws;       // 50000*128 bf16 (12.8MB)
    unsigned short* G     = hp_bf + 6400000;             // 50000*512 bf16 (51.2MB)
    unsigned short* Wih_b = G + 25600000;                // 512*128 (pre-scaled)
    unsigned short* Whh_b = Wih_b + 65536;               // 512*128 (pre-scaled)
    unsigned short* Wpt   = Whh_b + 65536;               // 128*256 (W_past^T)
    unsigned short* Wtt   = Wpt + 32768;                 // 128*256 (W^T)
    float*          bsum  = (float*)(Wtt + 32768);       // 512 (pre-scaled)

    prep_kernel<<<771, 256, 0, stream>>>(Wp, W, Wih, Whh, bih, bhh, Wih_b, Whh_b, Wpt, Wtt, bsum);
    hp_g_kernel<<<1563, 512, 0, stream>>>(h, Wpt, Wih_b, bsum, hp_bf, G);
    lstm_kernel<<<3125, 512, 0, stream>>>(hp_bf, agg, G, Whh_b, Wtt, out);
}

// Round 13
// 283.365 us; speedup vs baseline: 3.5625x; 1.0586x over previous
//
#include <hip/hip_runtime.h>

#define NN 50000
#define KSEQ 20
#define HN_OFF 6400000   // N*128
#define CN_OFF 12800000  // 2*N*128

using short8 = __attribute__((ext_vector_type(8))) short;
using f32x4  = __attribute__((ext_vector_type(4))) float;

__device__ __forceinline__ unsigned short f2bf(float f) {
    unsigned int u = __float_as_uint(f);
    return (unsigned short)((u + 0x7FFFu + ((u >> 16) & 1u)) >> 16);  // RNE
}
__device__ __forceinline__ float exp2x(float x) { float r; asm("v_exp_f32 %0, %1" : "=v"(r) : "v"(x)); return r; }
__device__ __forceinline__ float rcpx(float x)  { float r; asm("v_rcp_f32 %0, %1" : "=v"(r) : "v"(x)); return r; }

#define L2E 1.4426950408889634f
// gate pre-activations arrive PRE-SCALED (i,f,o by -l2e; g by +2*l2e)
__device__ __forceinline__ float sigp(float y)  { return rcpx(1.f + exp2x(y)); }
__device__ __forceinline__ float tanhp(float y) { return fmaf(-2.f, rcpx(1.f + exp2x(y)), 1.f); }

// ---- prep: bf16 weight packs (pre-scaled LSTM weights, transposes, bias sum) ----
__global__ void prep_kernel(const float* __restrict__ Wp, const float* __restrict__ W,
                            const float* __restrict__ Wih, const float* __restrict__ Whh,
                            const float* __restrict__ bih, const float* __restrict__ bhh,
                            unsigned short* __restrict__ Wih_b, unsigned short* __restrict__ Whh_b,
                            unsigned short* __restrict__ Wpt, unsigned short* __restrict__ Wtt,
                            float* __restrict__ bsum) {
    int tid = blockIdx.x * blockDim.x + threadIdx.x;
    if (tid < 65536) {  // gate scale: i,f,o -> -l2e ; g -> +2*l2e
        float sc = ((tid >> 14) == 2) ? (2.f * L2E) : (-L2E);
        Wih_b[tid] = f2bf(Wih[tid] * sc); return;
    }
    tid -= 65536;
    if (tid < 65536) {
        float sc = ((tid >> 14) == 2) ? (2.f * L2E) : (-L2E);
        Whh_b[tid] = f2bf(Whh[tid] * sc); return;
    }
    tid -= 65536;
    if (tid < 32768) { int j = tid >> 8, k = tid & 255; Wpt[tid] = f2bf(Wp[k * 128 + j]); return; }
    tid -= 32768;
    if (tid < 32768) { int j = tid >> 8, k = tid & 255; Wtt[tid] = f2bf(W[k * 128 + j]); return; }
    tid -= 32768;
    if (tid < 512) {
        float sc = ((tid >> 7) == 2) ? (2.f * L2E) : (-L2E);
        bsum[tid] = (bih[tid] + bhh[tid]) * sc;
    }
}

// ---- K1 (fused): hp = bf16(h @ W_past) -> global + LDS; G = bf16(hp @ W_ih^T + b)
// 32 rows/block, 8 waves (16 cols each).
__global__ __launch_bounds__(512, 2) void hp_g_kernel(const float* __restrict__ h,
                                                      const unsigned short* __restrict__ Wpt,
                                                      const unsigned short* __restrict__ Wih_b,
                                                      const float* __restrict__ bsum,
                                                      unsigned short* __restrict__ hp_bf,
                                                      unsigned short* __restrict__ G) {
    __shared__ __align__(16) unsigned char smem[24576];   // hstage 16KB @0, hpstage 8KB @16384
    const int tid = threadIdx.x;
    const int w = tid >> 6, l = tid & 63;
    const int l15 = l & 15, lq = l >> 4;
    const int base = blockIdx.x * 32;
    const int colj = w * 16 + l15;

    // stage h rows -> bf16 (32 rows x 512B, swizzled)
#pragma unroll
    for (int i = 0; i < 4; ++i) {
        int chunk = tid + 512 * i;
        int row = chunk >> 6, kc = chunk & 63;
        int grow = base + row;
        float4 v = make_float4(0.f, 0.f, 0.f, 0.f);
        if (grow < NN) v = *(const float4*)(h + (size_t)grow * 256 + kc * 4);
        ushort4 bv = make_ushort4(f2bf(v.x), f2bf(v.y), f2bf(v.z), f2bf(v.w));
        int off = (row * 512 + kc * 8) ^ ((row & 7) << 4);
        *(ushort4*)(smem + off) = bv;
    }
    __syncthreads();

    // ---- hp GEMM ----
    short8 bf[8];
#pragma unroll
    for (int kt = 0; kt < 8; ++kt)
        bf[kt] = *(const short8*)((const unsigned char*)Wpt + colj * 512 + kt * 64 + lq * 16);

    f32x4 acc[2];
    acc[0] = (f32x4){0.f, 0.f, 0.f, 0.f};
    acc[1] = acc[0];
#pragma unroll
    for (int kt = 0; kt < 8; ++kt) {
#pragma unroll
        for (int rt = 0; rt < 2; ++rt) {
            int arow = rt * 16 + l15;
            int off = (arow * 512 + kt * 64 + lq * 16) ^ ((arow & 7) << 4);
            short8 a = *(const short8*)(smem + off);
            acc[rt] = __builtin_amdgcn_mfma_f32_16x16x32_bf16(a, bf[kt], acc[rt], 0, 0, 0);
        }
    }
    // write hp to global + LDS (bf16)
#pragma unroll
    for (int rt = 0; rt < 2; ++rt)
#pragma unroll
        for (int r = 0; r < 4; ++r) {
            int row = rt * 16 + lq * 4 + r;
            int grow = base + row;
            unsigned short hb = f2bf(acc[rt][r]);
            if (grow < NN) hp_bf[(size_t)grow * 128 + colj] = hb;
            *(unsigned short*)(smem + 16384 + ((row * 256 + colj * 2) ^ ((row & 7) << 4))) = hb;
        }
    __syncthreads();

    // ---- G GEMM: 4 gates, K=128 from hpstage ----
    short8 bw4[4][4];
    float bi[4];
#pragma unroll
    for (int g = 0; g < 4; ++g) {
#pragma unroll
        for (int kt = 0; kt < 4; ++kt)
            bw4[g][kt] = *(const short8*)((const unsigned char*)Wih_b + (g * 128 + colj) * 256 + kt * 64 + lq * 16);
        bi[g] = bsum[g * 128 + colj];
    }
    const int off0 = (l15 * 256 + lq * 16) ^ ((l15 & 7) << 4);

    f32x4 ag[4][2];
#pragma unroll
    for (int g = 0; g < 4; ++g) { ag[g][0] = (f32x4){bi[g], bi[g], bi[g], bi[g]}; ag[g][1] = ag[g][0]; }
#pragma unroll
    for (int kt = 0; kt < 4; ++kt)
#pragma unroll
        for (int rt = 0; rt < 2; ++rt) {
            short8 a = *(const short8*)(smem + 16384 + rt * 4096 + (off0 ^ (kt << 6)));
#pragma unroll
            for (int g = 0; g < 4; ++g)
                ag[g][rt] = __builtin_amdgcn_mfma_f32_16x16x32_bf16(a, bw4[g][kt], ag[g][rt], 0, 0, 0);
        }
#pragma unroll
    for (int rt = 0; rt < 2; ++rt)
#pragma unroll
        for (int e = 0; e < 4; ++e) {
            int grow = base + rt * 16 + lq * 4 + e;
            if (grow < NN) {
                ushort4 pk = make_ushort4(f2bf(ag[0][rt][e]), f2bf(ag[1][rt][e]),
                                          f2bf(ag[2][rt][e]), f2bf(ag[3][rt][e]));
                *(ushort4*)(G + (size_t)grow * 512 + colj * 4) = pk;
            }
        }
}

// ---- K2: LSTM recurrence, 16 rows/block, 8 waves, 2 blocks/CU.
// Wave w = all 4 gates for cols w*16..+15 (W_hh = 64 regs, AGPR).
// gx prefetch distance 1, issued right after unpack (cover = h-GEMM + update + barrier).
// Fused cell update: 7 trans/elem (3 exp2 + 1 rcp for c; 2 exp2 + 1 rcp for h).
// LDS (14KB): hbuf0 @0, hbuf1 @4096, hpbuf @8192 (4KB), slab @12288 [t][row] 1280B.
#define SLAB 12288
template<int RP>
__device__ __forceinline__ void lstm_step(unsigned char* lds, int t,
    uint2 (&gx)[4], const short8 (&bw)[4][4], f32x4& cst,
    const unsigned char* Gp, const unsigned cb,
    const int off0, const int colj, const int lq, const int hwb, const int hswz,
    const int base, float* __restrict__ out)
{
    constexpr int NP = RP ^ 1;
    // idx(t+1): ONE b128 from transposed slab (rows lq*4..+3)
    int4 idx4;
    if (t < KSEQ - 1)
        idx4 = *(const int4*)(lds + SLAB + (t + 1) * 64 + lq * 16);

    // unpack gx(t) -> acc (frees gx regs)
    f32x4 acc[4];
#pragma unroll
    for (int e = 0; e < 4; ++e) {
        uint2 u = gx[e];
        acc[0][e] = __uint_as_float(u.x << 16);
        acc[1][e] = __uint_as_float(u.x & 0xFFFF0000u);
        acc[2][e] = __uint_as_float(u.y << 16);
        acc[3][e] = __uint_as_float(u.y & 0xFFFF0000u);
    }
    // issue gx(t+1) now — in flight across h-GEMM + update + barrier
    if (t < KSEQ - 1) {
        gx[0] = *(const uint2*)(Gp + (((unsigned)idx4.x << 10) + cb));
        gx[1] = *(const uint2*)(Gp + (((unsigned)idx4.y << 10) + cb));
        gx[2] = *(const uint2*)(Gp + (((unsigned)idx4.z << 10) + cb));
        gx[3] = *(const uint2*)(Gp + (((unsigned)idx4.w << 10) + cb));
    }
    if (t > 0) {  // h-GEMM: acc += h_t @ W_hh
        __builtin_amdgcn_s_setprio(1);
#pragma unroll
        for (int kt = 0; kt < 4; ++kt) {
            short8 a = *(const short8*)(lds + RP * 4096 + (off0 ^ (kt << 6)));
#pragma unroll
            for (int g = 0; g < 4; ++g)
                acc[g] = __builtin_amdgcn_mfma_f32_16x16x32_bf16(a, bw[g][kt], acc[g], 0, 0, 0);
        }
        __builtin_amdgcn_s_setprio(0);
    }
    // fused cell update -> h(t+1) into hbuf[NP]
#pragma unroll
    for (int e = 0; e < 4; ++e) {
        float Ai = 1.f + exp2x(acc[0][e]);          // sigma(i) = 1/Ai
        float Af = 1.f + exp2x(acc[1][e]);          // sigma(f) = 1/Af
        float B  = 1.f + exp2x(acc[2][e]);          // tanh(g)  = (B-2)/B
        float AiB = Ai * B;
        float c = fmaf(cst[e], AiB, Af * (B - 2.f)) * rcpx(Af * AiB);
        cst[e] = c;
        float C  = 1.f + exp2x((2.f * L2E) * c);    // tanh(c) = (C-2)/C
        float Do = 1.f + exp2x(acc[3][e]);          // sigma(o) = 1/Do
        float hv = (C - 2.f) * rcpx(C * Do);
        unsigned pk;
        asm("v_cvt_pk_bf16_f32 %0, %1, %2" : "=v"(pk) : "v"(hv), "v"(hv));
        *(unsigned short*)(lds + NP * 4096 + ((hwb + e * 256) ^ (hswz ^ (e << 4)))) = (unsigned short)pk;
        if (t == KSEQ - 1) {
            int grow = base + lq * 4 + e;            // 50000 = 16*3125: no tail
            out[HN_OFF + (size_t)grow * 128 + colj] = hv;
            out[CN_OFF + (size_t)grow * 128 + colj] = c;
        }
    }
    __syncthreads();  // h(t+1) visible; hbuf[RP] reads done (write buffer differs)
}

__global__ __launch_bounds__(512, 4) void lstm_kernel(const unsigned short* __restrict__ hp_bf,
                                                      const int* __restrict__ agg,
                                                      const unsigned short* __restrict__ G,
                                                      const unsigned short* __restrict__ Whh_b,
                                                      const unsigned short* __restrict__ Wtt,
                                                      float* __restrict__ out) {
    __shared__ __align__(16) unsigned char lds[14336];
    const int tid = threadIdx.x;
    const int w = tid >> 6, l = tid & 63;
    const int l15 = l & 15, lq = l >> 4;
    const int base = blockIdx.x * 16;
    const int colj = w * 16 + l15;

    // stage hp rows (@8192, 256 threads) and the TRANSPOSED 20x16 index slab (@12288)
    if (tid < 256) {
        int row = tid >> 4, c = tid & 15;
        uint4 v = *(const uint4*)((const unsigned char*)hp_bf + (size_t)(base + row) * 256 + c * 16);
        *(uint4*)(lds + 8192 + ((row * 256 + c * 16) ^ ((row & 7) << 4))) = v;
    }
    if (tid < 320) {                // slab[t][row] = agg[base+row][t]; coalesced read
        int row = tid / 20, t = tid - row * 20;
        *(int*)(lds + SLAB + t * 64 + row * 4) = agg[(size_t)base * KSEQ + tid];
    }

    // W_hh fragments: 4 gates x 4 k-tiles (K=128) -> 64 regs (AGPR)
    short8 bw[4][4];
#pragma unroll
    for (int g = 0; g < 4; ++g)
#pragma unroll
        for (int kt = 0; kt < 4; ++kt)
            bw[g][kt] = *(const short8*)((const unsigned char*)Whh_b + (g * 128 + colj) * 256 + kt * 64 + lq * 16);

    const int off0 = (l15 * 256 + lq * 16) ^ ((l15 & 7) << 4);
    const int hwb = lq * 1024 + colj * 2;
    const int hswz = (lq & 1) << 6;
    const unsigned char* Gp = (const unsigned char*)G;
    const unsigned cb = (unsigned)colj * 8;        // byte offset within a G row

    f32x4 cst = (f32x4){0.f, 0.f, 0.f, 0.f};
    __syncthreads();  // hpbuf + slab staged

    uint2 gx[4];
    {   // gx(0) from slab[0]
        int4 i4 = *(const int4*)(lds + SLAB + lq * 16);
        gx[0] = *(const uint2*)(Gp + (((unsigned)i4.x << 10) + cb));
        gx[1] = *(const uint2*)(Gp + (((unsigned)i4.y << 10) + cb));
        gx[2] = *(const uint2*)(Gp + (((unsigned)i4.z << 10) + cb));
        gx[3] = *(const uint2*)(Gp + (((unsigned)i4.w << 10) + cb));
    }

#pragma unroll 1
    for (int tt = 0; tt < KSEQ; tt += 2) {
        lstm_step<0>(lds, tt,     gx, bw, cst, Gp, cb, off0, colj, lq, hwb, hswz, base, out);
        lstm_step<1>(lds, tt + 1, gx, bw, cst, Gp, cb, off0, colj, lq, hwb, hswz, base, out);
    }
    // hbuf0 = h_20; hpbuf @8192 = own hp rows

    // epilogue: out = elu([hp | h_n] @ W)
    short8 bo[8];
#pragma unroll
    for (int kt = 0; kt < 8; ++kt)
        bo[kt] = *(const short8*)((const unsigned char*)Wtt + colj * 512 + kt * 64 + lq * 16);

    f32x4 a2 = (f32x4){0.f, 0.f, 0.f, 0.f};
#pragma unroll
    for (int kt = 0; kt < 4; ++kt) {
        short8 a = *(const short8*)(lds + 8192 + (off0 ^ (kt << 6)));   // hp
        a2 = __builtin_amdgcn_mfma_f32_16x16x32_bf16(a, bo[kt], a2, 0, 0, 0);
    }
#pragma unroll
    for (int kt = 0; kt < 4; ++kt) {
        short8 a = *(const short8*)(lds + (off0 ^ (kt << 6)));          // h_n (hbuf0)
        a2 = __builtin_amdgcn_mfma_f32_16x16x32_bf16(a, bo[kt + 4], a2, 0, 0, 0);
    }
#pragma unroll
    for (int e = 0; e < 4; ++e) {
        int grow = base + lq * 4 + e;
        float v = a2[e];
        out[(size_t)grow * 128 + colj] = (v > 0.f) ? v : (exp2x(L2E * v) - 1.f);
    }
}

extern "C" void kernel_launch(void* const* d_in, const int* in_sizes, int n_in,
                              void* d_out, int out_size, void* d_ws, size_t ws_size,
                              hipStream_t stream) {
    (void)in_sizes; (void)n_in; (void)out_size; (void)ws_size;
    const float* h   = (const float*)d_in[0];
    const int*   agg = (const int*)d_in[1];
    const float* Wp  = (const float*)d_in[2];
    const float* W   = (const float*)d_in[3];
    const float* Wih = (const float*)d_in[4];
    const float* Whh = (const float*)d_in[5];
    const float* bih = (const float*)d_in[6];
    const float* bhh = (const float*)d_in[7];
    float* out = (float*)d_out;

    unsigned short* hp_bf = (unsigned short*)d_ws;       // 50000*128 bf16 (12.8MB)
    unsigned short* G     = hp_bf + 6400000;             // 50000*512 bf16 (51.2MB)
    unsigned short* Wih_b = G + 25600000;                // 512*128 (pre-scaled)
    unsigned short* Whh_b = Wih_b + 65536;               // 512*128 (pre-scaled)
    unsigned short* Wpt   = Whh_b + 65536;               // 128*256 (W_past^T)
    unsigned short* Wtt   = Wpt + 32768;                 // 128*256 (W^T)
    float*          bsum  = (float*)(Wtt + 32768);       // 512 (pre-scaled)

    prep_kernel<<<771, 256, 0, stream>>>(Wp, W, Wih, Whh, bih, bhh, Wih_b, Whh_b, Wpt, Wtt, bsum);
    hp_g_kernel<<<1563, 512, 0, stream>>>(h, Wpt, Wih_b, bsum, hp_bf, G);
    lstm_kernel<<<3125, 512, 0, stream>>>(hp_bf, agg, G, Whh_b, Wtt, out);
}

// Round 14
// 281.931 us; speedup vs baseline: 3.5806x; 1.0051x over previous
//
#include <hip/hip_runtime.h>

#define NN 50000
#define KSEQ 20
#define HN_OFF 6400000   // N*128
#define CN_OFF 12800000  // 2*N*128

using short8 = __attribute__((ext_vector_type(8))) short;
using f32x4  = __attribute__((ext_vector_type(4))) float;

__device__ __forceinline__ unsigned short f2bf(float f) {
    unsigned int u = __float_as_uint(f);
    return (unsigned short)((u + 0x7FFFu + ((u >> 16) & 1u)) >> 16);  // RNE
}
__device__ __forceinline__ float exp2x(float x) { float r; asm("v_exp_f32 %0, %1" : "=v"(r) : "v"(x)); return r; }
__device__ __forceinline__ float rcpx(float x)  { float r; asm("v_rcp_f32 %0, %1" : "=v"(r) : "v"(x)); return r; }

#define L2E 1.4426950408889634f
__device__ __forceinline__ float sigp(float y)  { return rcpx(1.f + exp2x(y)); }
__device__ __forceinline__ float tanhp(float y) { return fmaf(-2.f, rcpx(1.f + exp2x(y)), 1.f); }

// async global->LDS (16 B per lane, linear dest = base + lane*16)
typedef const __attribute__((address_space(1))) unsigned int gu32;
typedef __attribute__((address_space(3))) unsigned int lu32;
__device__ __forceinline__ void gload_lds16(const void* g, void* l) {
    __builtin_amdgcn_global_load_lds((gu32*)g, (lu32*)l, 16, 0, 0);
}

// ---- prep: bf16 weight packs (pre-scaled LSTM weights, transposes, bias sum) ----
__global__ void prep_kernel(const float* __restrict__ Wp, const float* __restrict__ W,
                            const float* __restrict__ Wih, const float* __restrict__ Whh,
                            const float* __restrict__ bih, const float* __restrict__ bhh,
                            unsigned short* __restrict__ Wih_b, unsigned short* __restrict__ Whh_b,
                            unsigned short* __restrict__ Wpt, unsigned short* __restrict__ Wtt,
                            float* __restrict__ bsum) {
    int tid = blockIdx.x * blockDim.x + threadIdx.x;
    if (tid < 65536) {  // gate scale: i,f,o -> -l2e ; g -> +2*l2e
        float sc = ((tid >> 14) == 2) ? (2.f * L2E) : (-L2E);
        Wih_b[tid] = f2bf(Wih[tid] * sc); return;
    }
    tid -= 65536;
    if (tid < 65536) {
        float sc = ((tid >> 14) == 2) ? (2.f * L2E) : (-L2E);
        Whh_b[tid] = f2bf(Whh[tid] * sc); return;
    }
    tid -= 65536;
    if (tid < 32768) { int j = tid >> 8, k = tid & 255; Wpt[tid] = f2bf(Wp[k * 128 + j]); return; }
    tid -= 32768;
    if (tid < 32768) { int j = tid >> 8, k = tid & 255; Wtt[tid] = f2bf(W[k * 128 + j]); return; }
    tid -= 32768;
    if (tid < 512) {
        float sc = ((tid >> 7) == 2) ? (2.f * L2E) : (-L2E);
        bsum[tid] = (bih[tid] + bhh[tid]) * sc;
    }
}

// ---- K1 (fused): hp = bf16(h @ W_past) -> global + LDS; G = bf16(hp @ W_ih^T + b) ----
__global__ __launch_bounds__(512, 2) void hp_g_kernel(const float* __restrict__ h,
                                                      const unsigned short* __restrict__ Wpt,
                                                      const unsigned short* __restrict__ Wih_b,
                                                      const float* __restrict__ bsum,
                                                      unsigned short* __restrict__ hp_bf,
                                                      unsigned short* __restrict__ G) {
    __shared__ __align__(16) unsigned char smem[24576];   // hstage 16KB @0, hpstage 8KB @16384
    const int tid = threadIdx.x;
    const int w = tid >> 6, l = tid & 63;
    const int l15 = l & 15, lq = l >> 4;
    const int base = blockIdx.x * 32;
    const int colj = w * 16 + l15;

#pragma unroll
    for (int i = 0; i < 4; ++i) {
        int chunk = tid + 512 * i;
        int row = chunk >> 6, kc = chunk & 63;
        int grow = base + row;
        float4 v = make_float4(0.f, 0.f, 0.f, 0.f);
        if (grow < NN) v = *(const float4*)(h + (size_t)grow * 256 + kc * 4);
        ushort4 bv = make_ushort4(f2bf(v.x), f2bf(v.y), f2bf(v.z), f2bf(v.w));
        int off = (row * 512 + kc * 8) ^ ((row & 7) << 4);
        *(ushort4*)(smem + off) = bv;
    }
    __syncthreads();

    short8 bf[8];
#pragma unroll
    for (int kt = 0; kt < 8; ++kt)
        bf[kt] = *(const short8*)((const unsigned char*)Wpt + colj * 512 + kt * 64 + lq * 16);

    f32x4 acc[2];
    acc[0] = (f32x4){0.f, 0.f, 0.f, 0.f};
    acc[1] = acc[0];
#pragma unroll
    for (int kt = 0; kt < 8; ++kt) {
#pragma unroll
        for (int rt = 0; rt < 2; ++rt) {
            int arow = rt * 16 + l15;
            int off = (arow * 512 + kt * 64 + lq * 16) ^ ((arow & 7) << 4);
            short8 a = *(const short8*)(smem + off);
            acc[rt] = __builtin_amdgcn_mfma_f32_16x16x32_bf16(a, bf[kt], acc[rt], 0, 0, 0);
        }
    }
#pragma unroll
    for (int rt = 0; rt < 2; ++rt)
#pragma unroll
        for (int r = 0; r < 4; ++r) {
            int row = rt * 16 + lq * 4 + r;
            int grow = base + row;
            unsigned short hb = f2bf(acc[rt][r]);
            if (grow < NN) hp_bf[(size_t)grow * 128 + colj] = hb;
            *(unsigned short*)(smem + 16384 + ((row * 256 + colj * 2) ^ ((row & 7) << 4))) = hb;
        }
    __syncthreads();

    short8 bw4[4][4];
    float bi[4];
#pragma unroll
    for (int g = 0; g < 4; ++g) {
#pragma unroll
        for (int kt = 0; kt < 4; ++kt)
            bw4[g][kt] = *(const short8*)((const unsigned char*)Wih_b + (g * 128 + colj) * 256 + kt * 64 + lq * 16);
        bi[g] = bsum[g * 128 + colj];
    }
    const int off0 = (l15 * 256 + lq * 16) ^ ((l15 & 7) << 4);

    f32x4 ag[4][2];
#pragma unroll
    for (int g = 0; g < 4; ++g) { ag[g][0] = (f32x4){bi[g], bi[g], bi[g], bi[g]}; ag[g][1] = ag[g][0]; }
#pragma unroll
    for (int kt = 0; kt < 4; ++kt)
#pragma unroll
        for (int rt = 0; rt < 2; ++rt) {
            short8 a = *(const short8*)(smem + 16384 + rt * 4096 + (off0 ^ (kt << 6)));
#pragma unroll
            for (int g = 0; g < 4; ++g)
                ag[g][rt] = __builtin_amdgcn_mfma_f32_16x16x32_bf16(a, bw4[g][kt], ag[g][rt], 0, 0, 0);
        }
#pragma unroll
    for (int rt = 0; rt < 2; ++rt)
#pragma unroll
        for (int e = 0; e < 4; ++e) {
            int grow = base + rt * 16 + lq * 4 + e;
            if (grow < NN) {
                ushort4 pk = make_ushort4(f2bf(ag[0][rt][e]), f2bf(ag[1][rt][e]),
                                          f2bf(ag[2][rt][e]), f2bf(ag[3][rt][e]));
                *(ushort4*)(G + (size_t)grow * 512 + colj * 4) = pk;
            }
        }
}

// ---- K2: LSTM recurrence, 16 rows/block, 8 waves, 2 blocks/CU.
// Wave w owns all 4 gates for cols w*16..+15 (W_hh = 64 regs, AGPR).
// G rows for step t+1 staged via global_load_lds (wave w DMAs rows 2w,2w+1 = 1KB each)
// into double-buffered gxbuf; the step-end __syncthreads vmcnt(0) drain IS the sync.
// LDS (48.5KB): hbuf0 @0, hbuf1 @4096, hpbuf @8192, slab @12288 [t][row],
//               gxbuf @16384: 2 buffers x 16 rows x pitch 1040 (2-way bank aliasing).
#define SLAB 12288
#define GXB  16384
#define GXP  1040
#define GXS  16640

template<int RP>
__device__ __forceinline__ void lstm_step(unsigned char* lds, int t,
    const short8 (&bw)[4][4], f32x4& cst,
    const unsigned char* Gpl, const int slabw, const int gxw, const int gxr,
    const int off0, const int colj, const int lq, const int hwb, const int hswz,
    const int base, float* __restrict__ out)
{
    constexpr int NP = RP ^ 1;
    // issue DMA for gx(t+1) into gxbuf[NP] (wave-uniform rows 2w, 2w+1)
    if (t < KSEQ - 1) {
        int i0 = *(const int*)(lds + slabw + (t + 1) * 64);
        int i1 = *(const int*)(lds + slabw + (t + 1) * 64 + 4);
        gload_lds16(Gpl + ((size_t)(unsigned)i0 << 10), lds + gxw + NP * GXS);
        gload_lds16(Gpl + ((size_t)(unsigned)i1 << 10), lds + gxw + NP * GXS + GXP);
    }
    // gx(t) from gxbuf[RP] -> acc (4 x ds_read_b64, 2-way bank aliasing = free)
    f32x4 acc[4];
#pragma unroll
    for (int e = 0; e < 4; ++e) {
        uint2 u = *(const uint2*)(lds + gxr + RP * GXS + e * GXP);
        acc[0][e] = __uint_as_float(u.x << 16);
        acc[1][e] = __uint_as_float(u.x & 0xFFFF0000u);
        acc[2][e] = __uint_as_float(u.y << 16);
        acc[3][e] = __uint_as_float(u.y & 0xFFFF0000u);
    }
    if (t > 0) {  // h-GEMM: acc += h_t @ W_hh
        __builtin_amdgcn_s_setprio(1);
#pragma unroll
        for (int kt = 0; kt < 4; ++kt) {
            short8 a = *(const short8*)(lds + RP * 4096 + (off0 ^ (kt << 6)));
#pragma unroll
            for (int g = 0; g < 4; ++g)
                acc[g] = __builtin_amdgcn_mfma_f32_16x16x32_bf16(a, bw[g][kt], acc[g], 0, 0, 0);
        }
        __builtin_amdgcn_s_setprio(0);
    }
    // fused cell update -> h(t+1) into hbuf[NP]
#pragma unroll
    for (int e = 0; e < 4; ++e) {
        float Ai = 1.f + exp2x(acc[0][e]);          // sigma(i) = 1/Ai
        float Af = 1.f + exp2x(acc[1][e]);          // sigma(f) = 1/Af
        float B  = 1.f + exp2x(acc[2][e]);          // tanh(g)  = (B-2)/B
        float AiB = Ai * B;
        float c = fmaf(cst[e], AiB, Af * (B - 2.f)) * rcpx(Af * AiB);
        cst[e] = c;
        float C  = 1.f + exp2x((2.f * L2E) * c);    // tanh(c) = (C-2)/C
        float Do = 1.f + exp2x(acc[3][e]);          // sigma(o) = 1/Do
        float hv = (C - 2.f) * rcpx(C * Do);
        unsigned pk;
        asm("v_cvt_pk_bf16_f32 %0, %1, %2" : "=v"(pk) : "v"(hv), "v"(hv));
        *(unsigned short*)(lds + NP * 4096 + ((hwb + e * 256) ^ (hswz ^ (e << 4)))) = (unsigned short)pk;
        if (t == KSEQ - 1) {
            int grow = base + lq * 4 + e;            // 50000 = 16*3125: no tail
            __builtin_nontemporal_store(hv, &out[HN_OFF + (size_t)grow * 128 + colj]);
            __builtin_nontemporal_store(c,  &out[CN_OFF + (size_t)grow * 128 + colj]);
        }
    }
    __syncthreads();  // drains DMA(t+1) + publishes hbuf[NP]; hbuf/gxbuf[RP] reads done
}

__global__ __launch_bounds__(512, 4) void lstm_kernel(const unsigned short* __restrict__ hp_bf,
                                                      const int* __restrict__ agg,
                                                      const unsigned short* __restrict__ G,
                                                      const unsigned short* __restrict__ Whh_b,
                                                      const unsigned short* __restrict__ Wtt,
                                                      float* __restrict__ out) {
    __shared__ __align__(16) unsigned char lds[GXB + 2 * GXS];
    const int tid = threadIdx.x;
    const int w = tid >> 6, l = tid & 63;
    const int l15 = l & 15, lq = l >> 4;
    const int base = blockIdx.x * 16;
    const int colj = w * 16 + l15;

    // stage hp rows (@8192) and the TRANSPOSED 20x16 index slab (@12288)
    if (tid < 256) {
        int row = tid >> 4, c = tid & 15;
        uint4 v = *(const uint4*)((const unsigned char*)hp_bf + (size_t)(base + row) * 256 + c * 16);
        *(uint4*)(lds + 8192 + ((row * 256 + c * 16) ^ ((row & 7) << 4))) = v;
    }
    if (tid < 320) {                // slab[t][row] = agg[base+row][t]
        int row = tid / 20, t = tid - row * 20;
        *(int*)(lds + SLAB + t * 64 + row * 4) = agg[(size_t)base * KSEQ + tid];
    }
    __syncthreads();  // slab ready for DMA address reads

    const unsigned char* Gpl = (const unsigned char*)G + l * 16;  // per-lane G src base
    const int slabw = SLAB + w * 8;                                // this wave's 2 rows
    const int gxw   = GXB + w * 2080;                              // dest: rows 2w,2w+1

    // prologue DMA: gx(0) -> gxbuf0
    {
        int i0 = *(const int*)(lds + slabw);
        int i1 = *(const int*)(lds + slabw + 4);
        gload_lds16(Gpl + ((size_t)(unsigned)i0 << 10), lds + gxw);
        gload_lds16(Gpl + ((size_t)(unsigned)i1 << 10), lds + gxw + GXP);
    }

    // W_hh fragments: 4 gates x 4 k-tiles (K=128) -> 64 regs (AGPR)
    short8 bw[4][4];
#pragma unroll
    for (int g = 0; g < 4; ++g)
#pragma unroll
        for (int kt = 0; kt < 4; ++kt)
            bw[g][kt] = *(const short8*)((const unsigned char*)Whh_b + (g * 128 + colj) * 256 + kt * 64 + lq * 16);

    const int off0 = (l15 * 256 + lq * 16) ^ ((l15 & 7) << 4);
    const int hwb = lq * 1024 + colj * 2;
    const int hswz = (lq & 1) << 6;
    const int gxr = GXB + lq * (4 * GXP) + colj * 8;   // this thread's gx read base

    f32x4 cst = (f32x4){0.f, 0.f, 0.f, 0.f};
    __syncthreads();  // gxbuf0 landed (per-wave vmcnt drain + barrier)

#pragma unroll 1
    for (int tt = 0; tt < KSEQ; tt += 2) {
        lstm_step<0>(lds, tt,     bw, cst, Gpl, slabw, gxw, gxr, off0, colj, lq, hwb, hswz, base, out);
        lstm_step<1>(lds, tt + 1, bw, cst, Gpl, slabw, gxw, gxr, off0, colj, lq, hwb, hswz, base, out);
    }
    // hbuf0 = h_20; hpbuf @8192 = own hp rows

    // epilogue: out = elu([hp | h_n] @ W)
    short8 bo[8];
#pragma unroll
    for (int kt = 0; kt < 8; ++kt)
        bo[kt] = *(const short8*)((const unsigned char*)Wtt + colj * 512 + kt * 64 + lq * 16);

    f32x4 a2 = (f32x4){0.f, 0.f, 0.f, 0.f};
#pragma unroll
    for (int kt = 0; kt < 4; ++kt) {
        short8 a = *(const short8*)(lds + 8192 + (off0 ^ (kt << 6)));   // hp
        a2 = __builtin_amdgcn_mfma_f32_16x16x32_bf16(a, bo[kt], a2, 0, 0, 0);
    }
#pragma unroll
    for (int kt = 0; kt < 4; ++kt) {
        short8 a = *(const short8*)(lds + (off0 ^ (kt << 6)));          // h_n (hbuf0)
        a2 = __builtin_amdgcn_mfma_f32_16x16x32_bf16(a, bo[kt + 4], a2, 0, 0, 0);
    }
#pragma unroll
    for (int e = 0; e < 4; ++e) {
        int grow = base + lq * 4 + e;
        float v = a2[e];
        v = (v > 0.f) ? v : (exp2x(L2E * v) - 1.f);
        __builtin_nontemporal_store(v, &out[(size_t)grow * 128 + colj]);
    }
}

extern "C" void kernel_launch(void* const* d_in, const int* in_sizes, int n_in,
                              void* d_out, int out_size, void* d_ws, size_t ws_size,
                              hipStream_t stream) {
    (void)in_sizes; (void)n_in; (void)out_size; (void)ws_size;
    const float* h   = (const float*)d_in[0];
    const int*   agg = (const int*)d_in[1];
    const float* Wp  = (const float*)d_in[2];
    const float* W   = (const float*)d_in[3];
    const float* Wih = (const float*)d_in[4];
    const float* Whh = (const float*)d_in[5];
    const float* bih = (const float*)d_in[6];
    const float* bhh = (const float*)d_in[7];
    float* out = (float*)d_out;

    unsigned short* hp_bf = (unsigned short*)d_ws;       // 50000*128 bf16 (12.8MB)
    unsigned short* G     = hp_bf + 6400000;             // 50000*512 bf16 (51.2MB)
    unsigned short* Wih_b = G + 25600000;                // 512*128 (pre-scaled)
    unsigned short* Whh_b = Wih_b + 65536;               // 512*128 (pre-scaled)
    unsigned short* Wpt   = Whh_b + 65536;               // 128*256 (W_past^T)
    unsigned short* Wtt   = Wpt + 32768;                 // 128*256 (W^T)
    float*          bsum  = (float*)(Wtt + 32768);       // 512 (pre-scaled)

    prep_kernel<<<771, 256, 0, stream>>>(Wp, W, Wih, Whh, bih, bhh, Wih_b, Whh_b, Wpt, Wtt, bsum);
    hp_g_kernel<<<1563, 512, 0, stream>>>(h, Wpt, Wih_b, bsum, hp_bf, G);
    lstm_kernel<<<3125, 512, 0, stream>>>(hp_bf, agg, G, Whh_b, Wtt, out);
}